// Round 5
// baseline (3035.719 us; speedup 1.0000x reference)
//
#include <hip/hip_runtime.h>
#include <math.h>

// Problem constants
#define SEQL 128
#define NB   32
#define EMBD 300
#define HH   400      // hidden per direction
#define G4   1600     // 4*HH
#define FF   512
#define NLAB 9
#define NBLK 200      // persistent LSTM blocks: 2 dirs x 100 slices (4 hidden units each)

// ---------------- workspace layout (bytes) ----------------
static const size_t OFF_X    = 0;          // x [4096][300] f32 — dead after input GEMMs
static const size_t OFF_HBUF = 0;          // h dbuf [2 parity][2 dir][2 half][400][16] f32 (204,800)
static const size_t OFF_FLG  = 1048576;    // publish flags [2 dir][2 half][128] u32 — in dead x region
static const size_t OFF_XW   = 5242880;    // XWt [2][128][32][1600] f32 (52,428,800) dead after LSTM; he reuses it
static const size_t OFF_HE   = 5242880;    // he [4096][512] f32 (8,388,608) — after LSTM, before gemm_nn
static const size_t OFF_ENC  = 62914560;   // enc [4096][800] f32 (13,107,200) dead after proj GEMMs
static const size_t OFF_U    = 0;          // U [4096][9][516] f32 (76,087,296) overlays all of the above post-proj
static const size_t OFF_X1   = 76087296;   // x1 [4096][516] (8,454,144)
static const size_t OFF_Y1T  = 84541440;   // y1T [32][513][128] (8,404,992)
static const size_t OFF_KEYS = 92946432;   // keys u64 [32][16384] (4,194,304)
static const size_t OFF_WBP  = 97140736;   // Wb padded [9][513][516] (9,529,488)

// ---------------- agent-scope (IF-coherent, cache-bypassing) accessors ----------------
__device__ __forceinline__ float2 aload2f(const float2* p) {
  unsigned long long v = __hip_atomic_load((const unsigned long long*)p,
                                           __ATOMIC_RELAXED, __HIP_MEMORY_SCOPE_AGENT);
  union { unsigned long long u; float2 f; } c; c.u = v; return c.f;
}
__device__ __forceinline__ void astoref(float* p, float v) {
  __hip_atomic_store(p, v, __ATOMIC_RELAXED, __HIP_MEMORY_SCOPE_AGENT);
}
__device__ __forceinline__ unsigned afload(const unsigned* p) {
  return __hip_atomic_load(p, __ATOMIC_RELAXED, __HIP_MEMORY_SCOPE_AGENT);
}
__device__ __forceinline__ void afstore(unsigned* p, unsigned v) {
  __hip_atomic_store(p, v, __ATOMIC_RELAXED, __HIP_MEMORY_SCOPE_AGENT);
}

// ---------------- embedding gather ----------------
__global__ __launch_bounds__(256) void k_gather(const int* __restrict__ wi,
                                                const float* __restrict__ emb,
                                                float* __restrict__ x) {
  int m = blockIdx.x;
  int idx = wi[m];
  const float* src = emb + (size_t)idx * EMBD;
  float* dst = x + (size_t)m * EMBD;
  for (int e = threadIdx.x; e < EMBD; e += 256) dst[e] = src[e];
}

// ---------------- W_biaffine pad to stride 516 ----------------
__global__ __launch_bounds__(256) void k_wbpad(const float* __restrict__ wbi,
                                               float* __restrict__ wbp) {
  int tid = blockIdx.x * 256 + threadIdx.x;
  const int PER = 513 * 516;
  if (tid >= 9 * PER) return;
  int o = tid / PER;
  int r = tid - o * PER;
  int i = r / 516;
  int j = r - i * 516;
  wbp[tid] = (j < 513) ? wbi[(size_t)o * 513 * 513 + (size_t)i * 513 + j] : 0.f;
}

// ---------------- ones columns ----------------
__global__ __launch_bounds__(256) void k_ones(float* __restrict__ x1, float* __restrict__ y1T) {
  int tid = blockIdx.x * 256 + threadIdx.x;
  if (tid < 4096) {
    x1[(size_t)tid * 516 + 512] = 1.f;
  } else if (tid < 8192) {
    int r = tid - 4096;
    int bb = r >> 7, y = r & 127;
    y1T[((size_t)bb * 513 + 512) * 128 + y] = 1.f;
  }
}

// ---------------- he -> y1T transpose (coalesced both sides) ----------------
__global__ __launch_bounds__(256) void k_y1t(const float* __restrict__ he,
                                             float* __restrict__ y1T) {
  __shared__ float tile[32][33];
  int b = blockIdx.z;
  int n0 = blockIdx.x * 32, y0 = blockIdx.y * 32;
  int tx = threadIdx.x & 31, ty = threadIdx.x >> 5;
  for (int yy = ty; yy < 32; yy += 8)
    tile[yy][tx] = he[((size_t)b * 128 + y0 + yy) * 512 + n0 + tx];
  __syncthreads();
  for (int nn = ty; nn < 32; nn += 8)
    y1T[((size_t)b * 513 + n0 + nn) * 128 + y0 + tx] = tile[tx][nn];
}

// ---------------- tiled GEMM, f64 accumulate, f32 LDS staging (exact: cvt after read)
// mode 0: normal store (ldc); mode 2: XWt store [l][b][n] (coalesced)
__global__ __launch_bounds__(256) void k_gemm_nt(const float* __restrict__ A, int lda,
                                                 const float* __restrict__ W, int ldw,
                                                 const float* __restrict__ bias1,
                                                 const float* __restrict__ bias2,
                                                 float* __restrict__ C, int ldc,
                                                 int M, int N, int K, int mode) {
  __shared__ __align__(16) float As[16][68];
  __shared__ __align__(16) float Bs[16][68];
  int t = threadIdx.x;
  int m0 = blockIdx.x * 64, n0 = blockIdx.y * 64;
  int tm = t & 15, tn = t >> 4;
  int ar = t >> 2, akq = t & 3;
  double acc[4][4];
#pragma unroll
  for (int r = 0; r < 4; ++r)
#pragma unroll
    for (int c = 0; c < 4; ++c) acc[r][c] = 0.0;

  for (int k0 = 0; k0 < K; k0 += 16) {
    {
      const float* ap = A + (size_t)(m0 + ar) * lda + k0 + 4 * akq;
      float v0, v1, v2, v3;
      if (k0 + 4 * akq + 4 <= K) {
        float4 f = *(const float4*)ap; v0 = f.x; v1 = f.y; v2 = f.z; v3 = f.w;
      } else {
        v0 = (k0 + 4 * akq + 0 < K) ? ap[0] : 0.f;
        v1 = (k0 + 4 * akq + 1 < K) ? ap[1] : 0.f;
        v2 = (k0 + 4 * akq + 2 < K) ? ap[2] : 0.f;
        v3 = (k0 + 4 * akq + 3 < K) ? ap[3] : 0.f;
      }
      As[4 * akq + 0][ar] = v0; As[4 * akq + 1][ar] = v1;
      As[4 * akq + 2][ar] = v2; As[4 * akq + 3][ar] = v3;
    }
    {
      int nr = n0 + ar;
      float v0 = 0.f, v1 = 0.f, v2 = 0.f, v3 = 0.f;
      if (nr < N) {
        const float* wp = W + (size_t)nr * ldw + k0 + 4 * akq;
        if (k0 + 4 * akq + 4 <= K) {
          float4 f = *(const float4*)wp; v0 = f.x; v1 = f.y; v2 = f.z; v3 = f.w;
        } else {
          if (k0 + 4 * akq + 0 < K) v0 = wp[0];
          if (k0 + 4 * akq + 1 < K) v1 = wp[1];
          if (k0 + 4 * akq + 2 < K) v2 = wp[2];
          if (k0 + 4 * akq + 3 < K) v3 = wp[3];
        }
      }
      Bs[4 * akq + 0][ar] = v0; Bs[4 * akq + 1][ar] = v1;
      Bs[4 * akq + 2][ar] = v2; Bs[4 * akq + 3][ar] = v3;
    }
    __syncthreads();
#pragma unroll
    for (int kk = 0; kk < 16; ++kk) {
      float4 a4 = *(const float4*)&As[kk][4 * tm];
      float4 b4 = *(const float4*)&Bs[kk][4 * tn];
      double av[4] = {(double)a4.x, (double)a4.y, (double)a4.z, (double)a4.w};
      double bv[4] = {(double)b4.x, (double)b4.y, (double)b4.z, (double)b4.w};
#pragma unroll
      for (int r = 0; r < 4; ++r)
#pragma unroll
        for (int c = 0; c < 4; ++c) acc[r][c] = fma(av[r], bv[c], acc[r][c]);
    }
    __syncthreads();
  }
  double bn[4];
#pragma unroll
  for (int c = 0; c < 4; ++c) {
    int n = n0 + 4 * tn + c;
    double bv = 0.0;
    if (n < N) {
      if (bias1) bv += (double)bias1[n];
      if (bias2) bv += (double)bias2[n];
    }
    bn[c] = bv;
  }
  if (mode == 0) {
#pragma unroll
    for (int r = 0; r < 4; ++r) {
      int m = m0 + 4 * tm + r;
      float* cp = C + (size_t)m * ldc + n0 + 4 * tn;
      if (n0 + 4 * tn + 4 <= N) {
        float4 s = make_float4((float)(acc[r][0] + bn[0]), (float)(acc[r][1] + bn[1]),
                               (float)(acc[r][2] + bn[2]), (float)(acc[r][3] + bn[3]));
        *(float4*)cp = s;
      } else {
#pragma unroll
        for (int c = 0; c < 4; ++c)
          if (n0 + 4 * tn + c < N) cp[c] = (float)(acc[r][c] + bn[c]);
      }
    }
  } else {
    // XWt store: row = l*32 + b (m = b*128 + l), coalesced float4 in n
#pragma unroll
    for (int r = 0; r < 4; ++r) {
      int m = m0 + 4 * tm + r;
      int bb = m >> 7, l = m & 127;
      float* cp = C + ((size_t)l * 32 + bb) * G4 + n0 + 4 * tn;
      float4 s = make_float4((float)(acc[r][0] + bn[0]), (float)(acc[r][1] + bn[1]),
                             (float)(acc[r][2] + bn[2]), (float)(acc[r][3] + bn[3]));
      *(float4*)cp = s;
    }
  }
}

// ---------------- tiled GEMM f64-acc, f32 LDS staging, batched over o ----------------
__global__ __launch_bounds__(256) void k_gemm_nn(const float* __restrict__ A, int lda,
                                                 const float* __restrict__ Bm, int ldb,
                                                 size_t strideB,
                                                 float* __restrict__ C, int ldc,
                                                 int M, int N, int K) {
  __shared__ __align__(16) float As[16][68];
  __shared__ __align__(16) float Bs[16][68];
  int t = threadIdx.x;
  int o = blockIdx.z;
  const float* B = Bm + (size_t)o * strideB;
  float* Cb = C + (size_t)o * 516;
  int m0 = blockIdx.x * 64, n0 = blockIdx.y * 64;
  int tm = t & 15, tn = t >> 4;
  int ar = t >> 2, akq = t & 3;
  double acc[4][4];
#pragma unroll
  for (int r = 0; r < 4; ++r)
#pragma unroll
    for (int c = 0; c < 4; ++c) acc[r][c] = 0.0;

  for (int k0 = 0; k0 < K; k0 += 16) {
    {
      const float* ap = A + (size_t)(m0 + ar) * lda + k0 + 4 * akq;
      float v0, v1, v2, v3;
      if (k0 + 4 * akq + 4 <= K) {
        float4 f = *(const float4*)ap; v0 = f.x; v1 = f.y; v2 = f.z; v3 = f.w;
      } else {
        v0 = (k0 + 4 * akq + 0 < K) ? ap[0] : 0.f;
        v1 = (k0 + 4 * akq + 1 < K) ? ap[1] : 0.f;
        v2 = (k0 + 4 * akq + 2 < K) ? ap[2] : 0.f;
        v3 = (k0 + 4 * akq + 3 < K) ? ap[3] : 0.f;
      }
      As[4 * akq + 0][ar] = v0; As[4 * akq + 1][ar] = v1;
      As[4 * akq + 2][ar] = v2; As[4 * akq + 3][ar] = v3;
    }
    {
      int kr = k0 + (t >> 4);
      int nc = n0 + 4 * (t & 15);
      float v0 = 0.f, v1 = 0.f, v2 = 0.f, v3 = 0.f;
      if (kr < K) {
        const float* bp = B + (size_t)kr * ldb + nc;
        if (nc + 4 <= N) {
          float4 f = *(const float4*)bp; v0 = f.x; v1 = f.y; v2 = f.z; v3 = f.w;
        } else {
          if (nc + 0 < N) v0 = bp[0];
          if (nc + 1 < N) v1 = bp[1];
          if (nc + 2 < N) v2 = bp[2];
          if (nc + 3 < N) v3 = bp[3];
        }
      }
      int kk = t >> 4, nq = 4 * (t & 15);
      Bs[kk][nq + 0] = v0; Bs[kk][nq + 1] = v1;
      Bs[kk][nq + 2] = v2; Bs[kk][nq + 3] = v3;
    }
    __syncthreads();
#pragma unroll
    for (int kk = 0; kk < 16; ++kk) {
      float4 a4 = *(const float4*)&As[kk][4 * tm];
      float4 b4 = *(const float4*)&Bs[kk][4 * tn];
      double av[4] = {(double)a4.x, (double)a4.y, (double)a4.z, (double)a4.w};
      double bv[4] = {(double)b4.x, (double)b4.y, (double)b4.z, (double)b4.w};
#pragma unroll
      for (int r = 0; r < 4; ++r)
#pragma unroll
        for (int c = 0; c < 4; ++c) acc[r][c] = fma(av[r], bv[c], acc[r][c]);
    }
    __syncthreads();
  }
#pragma unroll
  for (int r = 0; r < 4; ++r) {
    int m = m0 + 4 * tm + r;
    float* cp = Cb + (size_t)m * ldc + n0 + 4 * tn;
    if (n0 + 4 * tn + 4 <= N) {
      *(float4*)cp = make_float4((float)acc[r][0], (float)acc[r][1],
                                 (float)acc[r][2], (float)acc[r][3]);
    } else {
#pragma unroll
      for (int c = 0; c < 4; ++c)
        if (n0 + 4 * tn + c < N) cp[c] = (float)acc[r][c];
    }
  }
}

// ---------------- persistent BiLSTM v7: batch-split software pipeline
// v6 post-mortem: per-step 7.1 µs dominated by the serial publish->MALL-visibility->poll->
// stage chain (~2-2.5 µs) which no byte reduction touches. v7 exploits that the 32 batch
// chains are INDEPENDENT: split into halves A (b0-15) / B (b16-31) with separate h-buffers
// and flags, processed alternately A(s),B(s),A(s+1)... When a block starts A(s), A's h(s-1)
// was published one half-slot ago and B(s)'s poll+stage+compute (~2.5 µs) sat in between —
// the MALL visibility latency is hidden; steady-state polls find flags already set.
// Lane map per half: kp=lane>>3 (8-way k-split), p=lane&7 (8 batch pairs); reduce via
// shfl_xor 8/16/32 (f64 partials — reorder effect ~1e-16). Per-half phase-split stage kept.
// WAR safety per half identical to v6 (disjoint buffers, flags gate parity overwrite).
__global__ __launch_bounds__(256, 1) void k_lstm3(const float* __restrict__ xwt,   // [2][128][32][1600] f32
                                                  const float* __restrict__ whh_f, // [1600][400]
                                                  const float* __restrict__ whh_b,
                                                  const int* __restrict__ word_idxs,
                                                  float* __restrict__ hbuf,        // [2][2][2][400][16] f32
                                                  unsigned* __restrict__ flags,    // [2][2][128] u32
                                                  float* __restrict__ enc) {
  __shared__ __align__(16) double Wvd[4 * 400 * 4];   // [u][k][g] f64, 51,200 B
  __shared__ __align__(16) float  Shf[6400];           // h half-tile [k 0..399][b 0..15] f32, 25,600 B
  int bid = blockIdx.x;
  int d = bid / 100, slice = bid - d * 100;
  const float* whh = d ? whh_b : whh_f;
  const float* xwd = xwt + (size_t)d * SEQL * 32 * G4;
  int t = threadIdx.x;

  // one-time: stage Whh rows for our 4 units x 4 gates into LDS as f64 [u][k][g]
  for (int pp = 0; pp < 16; ++pp) {
    int u = pp >> 2, g = pp & 3;
    const float* src = whh + (size_t)(g * 400 + slice * 4 + u) * 400;
    for (int k = t; k < 400; k += 256) Wvd[((size_t)u * 400 + k) * 4 + g] = (double)src[k];
  }

  int su = t >> 6;          // wave id = unit index within slice (0..3)
  int lane = t & 63;
  int kp = lane >> 3;       // k-phase (0..7) — high lane bits: conflict-free Shf reads
  int p  = lane & 7;        // batch-pair index within half (0..7)
  int sb2 = 2 * p;
  int kglob = slice * 4 + su;
  int cbl = sb2 + kp;       // batch col within half (valid for kp<2)
  double cstA = 0.0, cstB = 0.0;

  if (kp < 2) {
    astoref(&hbuf[(((size_t)1 * 2 + d) * 2 + 0) * 6400 + (size_t)kglob * 16 + cbl], 0.f);
    astoref(&hbuf[(((size_t)1 * 2 + d) * 2 + 1) * 6400 + (size_t)kglob * 16 + cbl], 0.f);
  }
  __syncthreads();                        // drain vmcnt (h init visible)
  if (t == 0) {
    afstore(&flags[((size_t)d * 2 + 0) * 128 + slice], 1u);   // publish #1 (initial h, half A)
    afstore(&flags[((size_t)d * 2 + 1) * 128 + slice], 1u);   // half B
  }

  for (int s = 0; s < SEQL; ++s) {
    int l = d ? (SEQL - 1 - s) : s;
    int rp = (s + 1) & 1, wp = s & 1;
    unsigned need = (unsigned)(s + 1);

#pragma unroll
    for (int hf = 0; hf < 2; ++hf) {
      unsigned* flg = flags + ((size_t)d * 2 + hf) * 128;
      const float2* hr2 = (const float2*)(hbuf + (((size_t)rp * 2 + d) * 2 + hf) * 6400);
      float* hwb = hbuf + (((size_t)wp * 2 + d) * 2 + hf) * 6400;
      double& cst = hf ? cstB : cstA;
      int cbg = hf * 16 + cbl;            // global batch column

      // prefetch xw gates + mask (latency hidden under poll/stage)
      float xw0 = 0.f, xw1 = 0.f, xw2 = 0.f, xw3 = 0.f;
      bool m = false;
      if (kp < 2) {
        const float* xp = xwd + ((size_t)l * 32 + cbg) * G4 + kglob;
        xw0 = xp[0]; xw1 = xp[400]; xw2 = xp[800]; xw3 = xp[1200];
        m = word_idxs[cbg * SEQL + l] > 0;
      }

      // wave 0 polls all 100 producer flags of this half (steady state: already set)
      if (su == 0) {
        bool mine = lane < 50;
        const unsigned* fpa = flg + lane;
        const unsigned* fpb = flg + 50 + lane;
        while (true) {
          unsigned va = mine ? afload(fpa) : 0xFFFFFFFFu;
          unsigned vb = mine ? afload(fpb) : 0xFFFFFFFFu;
          if (__ballot((va < need) || (vb < need)) == 0ull) break;
          __builtin_amdgcn_s_sleep(1);
        }
      }
      __syncthreads();   // flags ok; prior Shf consumption done

      // stage half-tile (400x16 f32 = 3200 float2): issue ALL 13 loads, phase-split write
      float2 r[13];
#pragma unroll
      for (int j = 0; j < 6; ++j)  r[j] = aload2f(&hr2[t + 256 * j]);
#pragma unroll
      for (int j = 6; j < 12; ++j) r[j] = aload2f(&hr2[1536 + t + 256 * (j - 6)]);
      if (t < 128) r[12] = aload2f(&hr2[3072 + t]);
      float2* Shf2 = (float2*)Shf;
#pragma unroll
      for (int j = 0; j < 6; ++j) Shf2[t + 256 * j] = r[j];
      __syncthreads();   // phase-1 (k<192) ready

      double acc[8];
#pragma unroll
      for (int z = 0; z < 8; ++z) acc[z] = 0.0;
#pragma unroll 4
      for (int kk = 0; kk < 24; ++kk) {
        int klocal = 8 * kk + kp;
        float2 hp = *(const float2*)&Shf[(size_t)klocal * 16 + sb2];
        const double2* wrow = (const double2*)&Wvd[((size_t)su * 400 + klocal) * 4];
        double2 w01 = wrow[0];   // gates i,f
        double2 w23 = wrow[1];   // gates g,o
        double hx = (double)hp.x, hy = (double)hp.y;
        acc[0] = fma(w01.x, hx, acc[0]);
        acc[1] = fma(w01.x, hy, acc[1]);
        acc[2] = fma(w01.y, hx, acc[2]);
        acc[3] = fma(w01.y, hy, acc[3]);
        acc[4] = fma(w23.x, hx, acc[4]);
        acc[5] = fma(w23.x, hy, acc[5]);
        acc[6] = fma(w23.y, hx, acc[6]);
        acc[7] = fma(w23.y, hy, acc[7]);
      }

      // phase-2 writes (disjoint LDS range; loads landed during phase-1 compute)
#pragma unroll
      for (int j = 6; j < 12; ++j) Shf2[1536 + t + 256 * (j - 6)] = r[j];
      if (t < 128) Shf2[3072 + t] = r[12];
      __syncthreads();   // phase-2 (k>=192) ready

#pragma unroll 4
      for (int kk = 24; kk < 50; ++kk) {
        int klocal = 8 * kk + kp;
        float2 hp = *(const float2*)&Shf[(size_t)klocal * 16 + sb2];
        const double2* wrow = (const double2*)&Wvd[((size_t)su * 400 + klocal) * 4];
        double2 w01 = wrow[0];
        double2 w23 = wrow[1];
        double hx = (double)hp.x, hy = (double)hp.y;
        acc[0] = fma(w01.x, hx, acc[0]);
        acc[1] = fma(w01.x, hy, acc[1]);
        acc[2] = fma(w01.y, hx, acc[2]);
        acc[3] = fma(w01.y, hy, acc[3]);
        acc[4] = fma(w23.x, hx, acc[4]);
        acc[5] = fma(w23.x, hy, acc[5]);
        acc[6] = fma(w23.y, hx, acc[6]);
        acc[7] = fma(w23.y, hy, acc[7]);
      }
      // reduce the 8-way k-split across kp groups (lane bits 3,4,5)
#pragma unroll
      for (int z = 0; z < 8; ++z) {
        acc[z] += __shfl_xor(acc[z], 8);
        acc[z] += __shfl_xor(acc[z], 16);
        acc[z] += __shfl_xor(acc[z], 32);
      }

      if (kp < 2) {
        double gi = acc[0 + kp] + (double)xw0;
        double gf = acc[2 + kp] + (double)xw1;
        double gg = acc[4 + kp] + (double)xw2;
        double go = acc[6 + kp] + (double)xw3;
        double si = (double)(1.f / (1.f + expf(-(float)gi)));
        double sf = (double)(1.f / (1.f + expf(-(float)gf)));
        double so = (double)(1.f / (1.f + expf(-(float)go)));
        double cn = sf * cst + si * (double)tanhf((float)gg);
        double hn = so * (double)tanhf((float)cn);
        float holdv = Shf[(size_t)kglob * 16 + cbl];   // own published h from step s-1
        float hv = m ? (float)hn : holdv;
        cst = m ? cn : cst;
        astoref(&hwb[(size_t)kglob * 16 + cbl], hv);
        enc[((size_t)cbg * SEQL + l) * 800 + d * 400 + kglob] = m ? (float)hn : 0.f;
      }
      __syncthreads();                          // drain vmcnt: h stores visible
      if (t == 0) afstore(&flg[slice], (unsigned)(s + 2));   // publish this half
    }
  }
}

// ---------------- stage 2: score + argmax per (b,x), emits sort keys ----------------
__global__ __launch_bounds__(128) void k_stage2(const float* __restrict__ U,
                                                const float* __restrict__ y1T,
                                                const int* __restrict__ labels,
                                                unsigned long long* __restrict__ keys) {
  __shared__ double Ur[4644];
  int bx = blockIdx.x;
  int b = bx >> 7, x = bx & 127;
  const float* Urow = U + (size_t)bx * 4644;
  for (int i = threadIdx.x; i < 4644; i += 128) Ur[i] = (double)Urow[i];
  __syncthreads();
  int y = threadIdx.x;
  double acc[9];
#pragma unroll
  for (int o = 0; o < 9; ++o) acc[o] = 0.0;
  const float* yb = y1T + (size_t)b * 513 * 128 + y;
  for (int j = 0; j < 513; ++j) {
    double yv = (double)yb[(size_t)j * 128];
#pragma unroll
    for (int o = 0; o < 9; ++o) acc[o] = fma(Ur[o * 516 + j], yv, acc[o]);
  }
  double best = acc[0];
  int bi = 0;
#pragma unroll
  for (int o = 1; o < 9; ++o) {
    if (acc[o] > best) { best = acc[o]; bi = o; }
  }
  int fi = x * 128 + y;
  int lab = labels[(size_t)bx * 128 + y];
  bool valid = (bi != 1) && (lab > 0);
  unsigned long long key;
  if (valid) {
    unsigned long long u = (unsigned long long)__double_as_longlong(best);
    unsigned long long mm = (u >> 63) ? ~u : (u | 0x8000000000000000ull);
    unsigned long long dm = ~mm;
    key = (dm & ~0x3FFFFull) | ((unsigned long long)(unsigned)fi << 4) |
          (unsigned long long)(unsigned)bi;
  } else {
    key = ~0ull;
  }
  keys[(size_t)b * 16384 + fi] = key;
}

// ---------------- decode phase 1: sort 2048-key chunks (8 per sentence, 256 blocks total)
// Also initializes the output to NON_ENTITY=1 (coalesced, spread across all blocks).
__global__ __launch_bounds__(256) void k_sortchunks(unsigned long long* __restrict__ keysg,
                                                    int* __restrict__ outp) {
  __shared__ unsigned long long s[2048];
  int c = blockIdx.x, b = blockIdx.y;
  unsigned long long* kg = keysg + (size_t)b * 16384 + (size_t)c * 2048;
  int* ob = outp + (size_t)b * 16384 + (size_t)c * 2048;
  int t = threadIdx.x;
  for (int i = t; i < 2048; i += 256) s[i] = kg[i];
  for (int i = t; i < 2048; i += 256) ob[i] = 1;
  __syncthreads();
  for (int k = 2; k <= 2048; k <<= 1) {
    for (int j = k >> 1; j > 0; j >>= 1) {
#pragma unroll
      for (int p = 0; p < 4; ++p) {
        int ii = p * 256 + t;                       // compare index 0..1023
        int i = ((ii & ~(j - 1)) << 1) | (ii & (j - 1));
        int ix = i | j;
        bool up = ((i & k) == 0);
        unsigned long long a = s[i], bb = s[ix];
        if (up ? (a > bb) : (a < bb)) { s[i] = bb; s[ix] = a; }
      }
      __syncthreads();
    }
  }
  for (int i = t; i < 2048; i += 256) kg[i] = s[i];
}

// ---------------- decode phase 2: per-sentence merge 8x2048 -> 16384 (ascending) ----------------
__global__ __launch_bounds__(1024) void k_merge8(unsigned long long* __restrict__ keysg) {
  extern __shared__ unsigned long long m[];   // 8192 u64 = 64 KB
  int b = blockIdx.x;
  int t = threadIdx.x;
  unsigned long long* kg = keysg + (size_t)b * 16384;

  // Round A: merge pairs of 2048-runs -> 4096-runs (two pairs per pass, both ascending)
  for (int pass = 0; pass < 2; ++pass) {
    unsigned long long* base = kg + (size_t)pass * 8192;
    for (int i = t; i < 2048; i += 1024) {
      m[i]        = base[i];                    // run0 fwd
      m[2048 + i] = base[2048 + 2047 - i];      // run1 rev -> bitonic block 0
      m[4096 + i] = base[4096 + i];             // run2 fwd
      m[6144 + i] = base[6144 + 2047 - i];      // run3 rev -> bitonic block 1
    }
    __syncthreads();
    for (int j = 2048; j > 0; j >>= 1) {
#pragma unroll
      for (int p = 0; p < 4; ++p) {
        int ii = p * 1024 + t;                  // compare idx 0..4095 over 8192 elems
        int i = ((ii & ~(j - 1)) << 1) | (ii & (j - 1));
        int ix = i | j;
        unsigned long long a = m[i], c = m[ix];
        if (a > c) { m[i] = c; m[ix] = a; }     // ascending in both 4096-blocks
      }
      __syncthreads();
    }
    for (int i = t; i < 8192; i += 1024) base[i] = m[i];
    __syncthreads();
  }

  // Round B: merge 4096+4096 -> 8192; half 0 ascending, half 1 DESCENDING (sets up round C)
  for (int pass = 0; pass < 2; ++pass) {
    unsigned long long* base = kg + (size_t)pass * 8192;
    for (int i = t; i < 4096; i += 1024) {
      m[i]        = base[i];                    // fwd
      m[4096 + i] = base[4096 + 4095 - i];      // rev -> bitonic 8192
    }
    __syncthreads();
    bool desc = (pass == 1);
    for (int j = 4096; j > 0; j >>= 1) {
#pragma unroll
      for (int p = 0; p < 4; ++p) {
        int ii = p * 1024 + t;                  // compare idx 0..4095
        int i = ((ii & ~(j - 1)) << 1) | (ii & (j - 1));
        int ix = i | j;
        unsigned long long a = m[i], c = m[ix];
        if (desc ? (a < c) : (a > c)) { m[i] = c; m[ix] = a; }
      }
      __syncthreads();
    }
    for (int i = t; i < 8192; i += 1024) base[i] = m[i];
    __syncthreads();
  }

  // Round C: asc ++ desc = bitonic 16384. Global stage j=8192, then two 8192 LDS asc merges.
  for (int i = t; i < 8192; i += 1024) {
    unsigned long long a = kg[i], c = kg[i + 8192];
    if (a > c) { kg[i] = c; kg[i + 8192] = a; }
  }
  __syncthreads();
  for (int half = 0; half < 2; ++half) {
    unsigned long long* base = kg + (size_t)half * 8192;
    for (int i = t; i < 8192; i += 1024) m[i] = base[i];
    __syncthreads();
    for (int j = 4096; j > 0; j >>= 1) {
#pragma unroll
      for (int p = 0; p < 4; ++p) {
        int ii = p * 1024 + t;
        int i = ((ii & ~(j - 1)) << 1) | (ii & (j - 1));
        int ix = i | j;
        unsigned long long a = m[i], c = m[ix];
        if (a > c) { m[i] = c; m[ix] = a; }
      }
      __syncthreads();
    }
    for (int i = t; i < 8192; i += 1024) base[i] = m[i];
    __syncthreads();
  }
}

// ---------------- decode helpers ----------------
__device__ __forceinline__ void rangemask(int i, int j,
                                          unsigned long long& r0, unsigned long long& r1) {
  if (i > j) { r0 = 0ull; r1 = 0ull; return; }
  unsigned long long u0, u1;
  if (j >= 64) { u0 = ~0ull; u1 = (j >= 127) ? ~0ull : ((1ull << (j - 63)) - 1ull); }
  else         { u0 = (j == 63) ? ~0ull : ((1ull << (j + 1)) - 1ull); u1 = 0ull; }
  unsigned long long f0, f1;
  if (i >= 64) { f0 = 0ull; f1 = (~0ull) << (i - 64); }
  else         { f0 = (~0ull) << i; f1 = ~0ull; }
  r0 = u0 & f0; r1 = u1 & f1;
}

// ---------------- decode phase 3: batched greedy NMS scan (decision-equivalent to serial)
__global__ __launch_bounds__(64) void k_scan(const unsigned long long* __restrict__ keysg,
                                             int* __restrict__ outp) {
  int b = blockIdx.x;
  int lane = threadIdx.x;
  const unsigned long long* kg = keysg + (size_t)b * 16384;
  int* ob = outp + (size_t)b * 16384;
  unsigned long long s0 = 0, s1 = 0, in0 = 0, in1 = 0;

  for (int base = 0; base < 16384; base += 64) {
    unsigned long long key = kg[base + lane];
    bool valid = (key != ~0ull);
    if (__ballot(valid) == 0ull) break;          // keys ascending: rest invalid too
    int fi = (int)((key >> 4) & 0x3FFFull);
    int ci = fi >> 7, cj = fi & 127, ca = (int)(key & 15ull);
    bool isR = (ci <= cj);
    unsigned long long r0, r1; rangemask(ci, cj, r0, r1);
    unsigned long long rangeB = __ballot(isR);
    unsigned long long unp = __ballot(valid);

    while (unp) {
      bool insb = (((ci < 64) ? (in0 >> ci) : (in1 >> (ci - 64))) & 1ull) != 0;
      bool ovl = ((r0 & s0) | (r1 & s1)) != 0ull;
      bool myc = insb || (isR && ovl);
      unsigned long long confl = __ballot(myc);
      unp &= ~confl;                              // monotone -> permanent reject
      if (!unp) break;
      unsigned long long er = unp & rangeB;
      if (er == 0ull) {
        // all remaining are non-conflicting points: accept all, update starts, done
        if ((unp >> lane) & 1ull) ob[fi] = ca;
        unsigned long long c0 = 0, c1 = 0;
        if ((unp >> lane) & 1ull) { if (ci < 64) c0 = 1ull << ci; else c1 = 1ull << (ci - 64); }
#pragma unroll
        for (int off = 32; off; off >>= 1) { c0 |= __shfl_xor(c0, off); c1 |= __shfl_xor(c1, off); }
        s0 |= c0; s1 |= c1;
        break;
      }
      int r = __ffsll((long long)er) - 1;
      unsigned long long below = (r == 0) ? 0ull : ((1ull << r) - 1ull);
      unsigned long long pb = unp & below;        // all points (earlier ranges rejected/processed)
      if (pb) {
        if ((pb >> lane) & 1ull) ob[fi] = ca;
        unsigned long long c0 = 0, c1 = 0;
        if ((pb >> lane) & 1ull) { if (ci < 64) c0 = 1ull << ci; else c1 = 1ull << (ci - 64); }
#pragma unroll
        for (int off = 32; off; off >>= 1) { c0 |= __shfl_xor(c0, off); c1 |= __shfl_xor(c1, off); }
        s0 |= c0; s1 |= c1;
        unp &= ~pb;
      }
      // decide range candidate r against the updated starts
      int wi = __shfl(ci, r), wj = __shfl(cj, r), wa = __shfl(ca, r), wfi = __shfl(fi, r);
      unsigned long long rr0, rr1; rangemask(wi, wj, rr0, rr1);
      bool rin = (((wi < 64) ? (in0 >> wi) : (in1 >> (wi - 64))) & 1ull) != 0;
      bool rovl = ((rr0 & s0) | (rr1 & s1)) != 0ull;
      if (!(rin || rovl)) {
        if (lane == r) ob[wfi] = wa;
        if (wi < 64) s0 |= 1ull << wi; else s1 |= 1ull << (wi - 64);
        in0 |= rr0; in1 |= rr1;
      }
      unp &= ~(1ull << r);
    }
  }
}

extern "C" void kernel_launch(void* const* d_in, const int* in_sizes, int n_in,
                              void* d_out, int out_size, void* d_ws, size_t ws_size,
                              hipStream_t stream) {
  const int*   word_idxs = (const int*)d_in[0];
  const int*   labels    = (const int*)d_in[1];
  const float* word_emb  = (const float*)d_in[2];
  const float* Wih_f = (const float*)d_in[3];
  const float* Whh_f = (const float*)d_in[4];
  const float* bih_f = (const float*)d_in[5];
  const float* bhh_f = (const float*)d_in[6];
  const float* Wih_b = (const float*)d_in[7];
  const float* Whh_b = (const float*)d_in[8];
  const float* bih_b = (const float*)d_in[9];
  const float* bhh_b = (const float*)d_in[10];
  const float* W_start = (const float*)d_in[11];
  const float* b_start = (const float*)d_in[12];
  const float* W_end   = (const float*)d_in[13];
  const float* b_end   = (const float*)d_in[14];
  const float* W_bi    = (const float*)d_in[15];

  char* ws = (char*)d_ws;
  float* x    = (float*)(ws + OFF_X);
  float* hbuf = (float*)(ws + OFF_HBUF);
  unsigned* flags = (unsigned*)(ws + OFF_FLG);
  float* XWt  = (float*)(ws + OFF_XW);
  float* he   = (float*)(ws + OFF_HE);
  float* enc  = (float*)(ws + OFF_ENC);
  float* U    = (float*)(ws + OFF_U);
  float* x1   = (float*)(ws + OFF_X1);
  float* y1T  = (float*)(ws + OFF_Y1T);
  float* Wbp  = (float*)(ws + OFF_WBP);
  unsigned long long* keys = (unsigned long long*)(ws + OFF_KEYS);
  int* outp = (int*)d_out;

  // 1. embedding gather
  k_gather<<<4096, 256, 0, stream>>>(word_idxs, word_emb, x);
  // 2. input-gate GEMMs, bias folded, stored coalesced as XWt[d][l][b][1600]
  dim3 g2(64, 25);
  k_gemm_nt<<<g2, 256, 0, stream>>>(x, EMBD, Wih_f, EMBD, bih_f, bhh_f,
                                    XWt, 0, 4096, G4, EMBD, 2);
  k_gemm_nt<<<g2, 256, 0, stream>>>(x, EMBD, Wih_b, EMBD, bih_b, bhh_b,
                                    XWt + (size_t)SEQL * 32 * G4, 0, 4096, G4, EMBD, 2);
  // 3. flags zero (x region now dead), then persistent LSTM (flag-synced)
  hipMemsetAsync(ws + OFF_FLG, 0, 4096, stream);
  k_lstm3<<<NBLK, 256, 0, stream>>>(XWt, Whh_f, Whh_b, word_idxs, hbuf, flags, enc);
  // 4. projections: x1 (coalesced) and he (coalesced) -> y1T via LDS transpose
  dim3 g4(64, 8);
  k_gemm_nt<<<g4, 256, 0, stream>>>(enc, 800, W_start, 800, b_start, nullptr,
                                    x1, 516, 4096, FF, 800, 0);
  k_gemm_nt<<<g4, 256, 0, stream>>>(enc, 800, W_end, 800, b_end, nullptr,
                                    he, 512, 4096, FF, 800, 0);
  dim3 gt(16, 4, 32);
  k_y1t<<<gt, 256, 0, stream>>>(he, y1T);
  k_ones<<<32, 256, 0, stream>>>(x1, y1T);
  // 5. biaffine stage 1: U[b,x][o][j] = sum_i x1[b,x,i] W[o,i,j]
  k_wbpad<<<(9 * 513 * 516 + 255) / 256, 256, 0, stream>>>(W_bi, Wbp);
  dim3 g5(64, 9, 9);
  k_gemm_nn<<<g5, 256, 0, stream>>>(x1, 516, Wbp, 516, (size_t)513 * 516,
                                    U, 4644, 4096, 513, 513);
  // 6. stage 2 + argmax + key build
  k_stage2<<<4096, 128, 0, stream>>>(U, y1T, labels, keys);
  // 7. decode: chunk sort (full GPU) -> per-sentence merge -> batched NMS scan
  dim3 gs(8, 32);
  k_sortchunks<<<gs, 256, 0, stream>>>(keys, outp);
  k_merge8<<<32, 1024, 65536, stream>>>(keys);
  k_scan<<<32, 64, 0, stream>>>(keys, outp);
}

// Round 6
// 2630.064 us; speedup vs baseline: 1.1542x; 1.1542x over previous
//
#include <hip/hip_runtime.h>
#include <math.h>

// Problem constants
#define SEQL 128
#define NB   32
#define EMBD 300
#define HH   400      // hidden per direction
#define G4   1600     // 4*HH
#define FF   512
#define NLAB 9
#define NBLK 200      // persistent LSTM blocks: 2 dirs x 100 slices (4 hidden units each)

// ---------------- workspace layout (bytes) ----------------
static const size_t OFF_X    = 0;          // x [4096][300] f32 — dead after input GEMMs
static const size_t OFF_HBUF = 0;          // h double-buffer [2][2][400][32] f32 (204,800) — live only in k_lstm3
static const size_t OFF_FLG  = 1048576;    // publish flags [2][128] u32 — in dead x region
static const size_t OFF_XW   = 5242880;    // XWt [2][128][32][1600] f32 (52,428,800) dead after LSTM; he reuses it
static const size_t OFF_HE   = 5242880;    // he [4096][512] f32 (8,388,608) — after LSTM, before gemm_nn
static const size_t OFF_ENC  = 62914560;   // enc [4096][800] f32 (13,107,200) dead after proj GEMMs
static const size_t OFF_U    = 0;          // U [4096][9][516] f32 (76,087,296) overlays all of the above post-proj
static const size_t OFF_X1   = 76087296;   // x1 [4096][516] (8,454,144)
static const size_t OFF_Y1T  = 84541440;   // y1T [32][513][128] (8,404,992)
static const size_t OFF_KEYS = 92946432;   // keys u64 [32][16384] (4,194,304)
static const size_t OFF_WBP  = 97140736;   // Wb padded [9][513][516] (9,529,488)

// ---------------- agent-scope (IF-coherent, cache-bypassing) accessors ----------------
__device__ __forceinline__ float2 aload2f(const float2* p) {
  unsigned long long v = __hip_atomic_load((const unsigned long long*)p,
                                           __ATOMIC_RELAXED, __HIP_MEMORY_SCOPE_AGENT);
  union { unsigned long long u; float2 f; } c; c.u = v; return c.f;
}
__device__ __forceinline__ void astoref(float* p, float v) {
  __hip_atomic_store(p, v, __ATOMIC_RELAXED, __HIP_MEMORY_SCOPE_AGENT);
}
__device__ __forceinline__ unsigned afload(const unsigned* p) {
  return __hip_atomic_load(p, __ATOMIC_RELAXED, __HIP_MEMORY_SCOPE_AGENT);
}
__device__ __forceinline__ void afstore(unsigned* p, unsigned v) {
  __hip_atomic_store(p, v, __ATOMIC_RELAXED, __HIP_MEMORY_SCOPE_AGENT);
}

// ---------------- embedding gather ----------------
__global__ __launch_bounds__(256) void k_gather(const int* __restrict__ wi,
                                                const float* __restrict__ emb,
                                                float* __restrict__ x) {
  int m = blockIdx.x;
  int idx = wi[m];
  const float* src = emb + (size_t)idx * EMBD;
  float* dst = x + (size_t)m * EMBD;
  for (int e = threadIdx.x; e < EMBD; e += 256) dst[e] = src[e];
}

// ---------------- W_biaffine pad to stride 516 ----------------
__global__ __launch_bounds__(256) void k_wbpad(const float* __restrict__ wbi,
                                               float* __restrict__ wbp) {
  int tid = blockIdx.x * 256 + threadIdx.x;
  const int PER = 513 * 516;
  if (tid >= 9 * PER) return;
  int o = tid / PER;
  int r = tid - o * PER;
  int i = r / 516;
  int j = r - i * 516;
  wbp[tid] = (j < 513) ? wbi[(size_t)o * 513 * 513 + (size_t)i * 513 + j] : 0.f;
}

// ---------------- ones columns ----------------
__global__ __launch_bounds__(256) void k_ones(float* __restrict__ x1, float* __restrict__ y1T) {
  int tid = blockIdx.x * 256 + threadIdx.x;
  if (tid < 4096) {
    x1[(size_t)tid * 516 + 512] = 1.f;
  } else if (tid < 8192) {
    int r = tid - 4096;
    int bb = r >> 7, y = r & 127;
    y1T[((size_t)bb * 513 + 512) * 128 + y] = 1.f;
  }
}

// ---------------- he -> y1T transpose (coalesced both sides) ----------------
__global__ __launch_bounds__(256) void k_y1t(const float* __restrict__ he,
                                             float* __restrict__ y1T) {
  __shared__ float tile[32][33];
  int b = blockIdx.z;
  int n0 = blockIdx.x * 32, y0 = blockIdx.y * 32;
  int tx = threadIdx.x & 31, ty = threadIdx.x >> 5;
  for (int yy = ty; yy < 32; yy += 8)
    tile[yy][tx] = he[((size_t)b * 128 + y0 + yy) * 512 + n0 + tx];
  __syncthreads();
  for (int nn = ty; nn < 32; nn += 8)
    y1T[((size_t)b * 513 + n0 + nn) * 128 + y0 + tx] = tile[tx][nn];
}

// ---------------- tiled GEMM, f64 accumulate, f32 LDS staging (exact: cvt after read)
// v8: 128x64 tile, 8x4 acc per thread (512 FMA per k0-tile vs 256) — halves barrier and
// staging cost per FMA. A-fragment = cols {4tm, 64+4tm} so LDS reads stay 2-way (free).
// mode 0: normal store (ldc); mode 2: XWt store [l][b][n] (coalesced). M must be mult of 128.
__global__ __launch_bounds__(256) void k_gemm_nt(const float* __restrict__ A, int lda,
                                                 const float* __restrict__ W, int ldw,
                                                 const float* __restrict__ bias1,
                                                 const float* __restrict__ bias2,
                                                 float* __restrict__ C, int ldc,
                                                 int M, int N, int K, int mode) {
  __shared__ __align__(16) float As[16][132];
  __shared__ __align__(16) float Bs[16][68];
  int t = threadIdx.x;
  int m0 = blockIdx.x * 128, n0 = blockIdx.y * 64;
  int tm = t & 15, tn = t >> 4;
  int ar = t >> 1, akq = t & 1;      // A stage: row m0+ar, 8 floats at k0+8*akq
  int br = t >> 2, bkq = t & 3;      // B stage: row n0+br, 4 floats at k0+4*bkq
  double acc[8][4];
#pragma unroll
  for (int r = 0; r < 8; ++r)
#pragma unroll
    for (int c = 0; c < 4; ++c) acc[r][c] = 0.0;

  for (int k0 = 0; k0 < K; k0 += 16) {
    {
      const float* ap = A + (size_t)(m0 + ar) * lda + k0 + 8 * akq;
      float v[8];
      if (k0 + 8 * akq + 8 <= K) {
        float4 f0 = *(const float4*)ap;
        float4 f1 = *(const float4*)(ap + 4);
        v[0] = f0.x; v[1] = f0.y; v[2] = f0.z; v[3] = f0.w;
        v[4] = f1.x; v[5] = f1.y; v[6] = f1.z; v[7] = f1.w;
      } else {
#pragma unroll
        for (int i = 0; i < 8; ++i) v[i] = (k0 + 8 * akq + i < K) ? ap[i] : 0.f;
      }
#pragma unroll
      for (int i = 0; i < 8; ++i) As[8 * akq + i][ar] = v[i];
    }
    {
      int nr = n0 + br;
      float v0 = 0.f, v1 = 0.f, v2 = 0.f, v3 = 0.f;
      if (nr < N) {
        const float* wp = W + (size_t)nr * ldw + k0 + 4 * bkq;
        if (k0 + 4 * bkq + 4 <= K) {
          float4 f = *(const float4*)wp; v0 = f.x; v1 = f.y; v2 = f.z; v3 = f.w;
        } else {
          if (k0 + 4 * bkq + 0 < K) v0 = wp[0];
          if (k0 + 4 * bkq + 1 < K) v1 = wp[1];
          if (k0 + 4 * bkq + 2 < K) v2 = wp[2];
          if (k0 + 4 * bkq + 3 < K) v3 = wp[3];
        }
      }
      Bs[4 * bkq + 0][br] = v0; Bs[4 * bkq + 1][br] = v1;
      Bs[4 * bkq + 2][br] = v2; Bs[4 * bkq + 3][br] = v3;
    }
    __syncthreads();
#pragma unroll
    for (int kk = 0; kk < 16; ++kk) {
      float4 a0 = *(const float4*)&As[kk][4 * tm];
      float4 a1 = *(const float4*)&As[kk][64 + 4 * tm];
      float4 b4 = *(const float4*)&Bs[kk][4 * tn];
      double av[8] = {(double)a0.x, (double)a0.y, (double)a0.z, (double)a0.w,
                      (double)a1.x, (double)a1.y, (double)a1.z, (double)a1.w};
      double bv[4] = {(double)b4.x, (double)b4.y, (double)b4.z, (double)b4.w};
#pragma unroll
      for (int r = 0; r < 8; ++r)
#pragma unroll
        for (int c = 0; c < 4; ++c) acc[r][c] = fma(av[r], bv[c], acc[r][c]);
    }
    __syncthreads();
  }
  double bn[4];
#pragma unroll
  for (int c = 0; c < 4; ++c) {
    int n = n0 + 4 * tn + c;
    double bv = 0.0;
    if (n < N) {
      if (bias1) bv += (double)bias1[n];
      if (bias2) bv += (double)bias2[n];
    }
    bn[c] = bv;
  }
  if (mode == 0) {
#pragma unroll
    for (int rr = 0; rr < 8; ++rr) {
      int m = m0 + ((rr < 4) ? (4 * tm + rr) : (64 + 4 * tm + rr - 4));
      float* cp = C + (size_t)m * ldc + n0 + 4 * tn;
      if (n0 + 4 * tn + 4 <= N) {
        float4 s = make_float4((float)(acc[rr][0] + bn[0]), (float)(acc[rr][1] + bn[1]),
                               (float)(acc[rr][2] + bn[2]), (float)(acc[rr][3] + bn[3]));
        *(float4*)cp = s;
      } else {
#pragma unroll
        for (int c = 0; c < 4; ++c)
          if (n0 + 4 * tn + c < N) cp[c] = (float)(acc[rr][c] + bn[c]);
      }
    }
  } else {
    // XWt store: row = l*32 + b (m = b*128 + l), coalesced float4 in n
#pragma unroll
    for (int rr = 0; rr < 8; ++rr) {
      int m = m0 + ((rr < 4) ? (4 * tm + rr) : (64 + 4 * tm + rr - 4));
      int bb = m >> 7, l = m & 127;
      float* cp = C + ((size_t)l * 32 + bb) * G4 + n0 + 4 * tn;
      float4 s = make_float4((float)(acc[rr][0] + bn[0]), (float)(acc[rr][1] + bn[1]),
                             (float)(acc[rr][2] + bn[2]), (float)(acc[rr][3] + bn[3]));
      *(float4*)cp = s;
    }
  }
}

// ---------------- tiled GEMM f64-acc, f32 LDS staging, batched over o ----------------
// v8: same 128x64 / 8x4 upgrade as k_gemm_nt. M must be mult of 128 (M=4096).
__global__ __launch_bounds__(256) void k_gemm_nn(const float* __restrict__ A, int lda,
                                                 const float* __restrict__ Bm, int ldb,
                                                 size_t strideB,
                                                 float* __restrict__ C, int ldc,
                                                 int M, int N, int K) {
  __shared__ __align__(16) float As[16][132];
  __shared__ __align__(16) float Bs[16][68];
  int t = threadIdx.x;
  int o = blockIdx.z;
  const float* B = Bm + (size_t)o * strideB;
  float* Cb = C + (size_t)o * 516;
  int m0 = blockIdx.x * 128, n0 = blockIdx.y * 64;
  int tm = t & 15, tn = t >> 4;
  int ar = t >> 1, akq = t & 1;
  double acc[8][4];
#pragma unroll
  for (int r = 0; r < 8; ++r)
#pragma unroll
    for (int c = 0; c < 4; ++c) acc[r][c] = 0.0;

  for (int k0 = 0; k0 < K; k0 += 16) {
    {
      const float* ap = A + (size_t)(m0 + ar) * lda + k0 + 8 * akq;
      float v[8];
      if (k0 + 8 * akq + 8 <= K) {
        float4 f0 = *(const float4*)ap;
        float4 f1 = *(const float4*)(ap + 4);
        v[0] = f0.x; v[1] = f0.y; v[2] = f0.z; v[3] = f0.w;
        v[4] = f1.x; v[5] = f1.y; v[6] = f1.z; v[7] = f1.w;
      } else {
#pragma unroll
        for (int i = 0; i < 8; ++i) v[i] = (k0 + 8 * akq + i < K) ? ap[i] : 0.f;
      }
#pragma unroll
      for (int i = 0; i < 8; ++i) As[8 * akq + i][ar] = v[i];
    }
    {
      int kr = k0 + (t >> 4);
      int nc = n0 + 4 * (t & 15);
      float v0 = 0.f, v1 = 0.f, v2 = 0.f, v3 = 0.f;
      if (kr < K) {
        const float* bp = B + (size_t)kr * ldb + nc;
        if (nc + 4 <= N) {
          float4 f = *(const float4*)bp; v0 = f.x; v1 = f.y; v2 = f.z; v3 = f.w;
        } else {
          if (nc + 0 < N) v0 = bp[0];
          if (nc + 1 < N) v1 = bp[1];
          if (nc + 2 < N) v2 = bp[2];
          if (nc + 3 < N) v3 = bp[3];
        }
      }
      int kk = t >> 4, nq = 4 * (t & 15);
      Bs[kk][nq + 0] = v0; Bs[kk][nq + 1] = v1;
      Bs[kk][nq + 2] = v2; Bs[kk][nq + 3] = v3;
    }
    __syncthreads();
#pragma unroll
    for (int kk = 0; kk < 16; ++kk) {
      float4 a0 = *(const float4*)&As[kk][4 * tm];
      float4 a1 = *(const float4*)&As[kk][64 + 4 * tm];
      float4 b4 = *(const float4*)&Bs[kk][4 * tn];
      double av[8] = {(double)a0.x, (double)a0.y, (double)a0.z, (double)a0.w,
                      (double)a1.x, (double)a1.y, (double)a1.z, (double)a1.w};
      double bv[4] = {(double)b4.x, (double)b4.y, (double)b4.z, (double)b4.w};
#pragma unroll
      for (int r = 0; r < 8; ++r)
#pragma unroll
        for (int c = 0; c < 4; ++c) acc[r][c] = fma(av[r], bv[c], acc[r][c]);
    }
    __syncthreads();
  }
#pragma unroll
  for (int rr = 0; rr < 8; ++rr) {
    int m = m0 + ((rr < 4) ? (4 * tm + rr) : (64 + 4 * tm + rr - 4));
    float* cp = Cb + (size_t)m * ldc + n0 + 4 * tn;
    if (n0 + 4 * tn + 4 <= N) {
      *(float4*)cp = make_float4((float)acc[rr][0], (float)acc[rr][1],
                                 (float)acc[rr][2], (float)acc[rr][3]);
    } else {
#pragma unroll
      for (int c = 0; c < 4; ++c)
        if (n0 + 4 * tn + c < N) cp[c] = (float)acc[rr][c];
    }
  }
}

// ---------------- persistent BiLSTM v6 (reverted from v7 regression): f32 h-exchange +
// phase-split stage. v7 lesson: at 200-block scale, per-sync-round fixed cost (~2.5 µs)
// exceeds the latency it can hide — never increase sync-round count. v6 = best known.
__global__ __launch_bounds__(256, 1) void k_lstm3(const float* __restrict__ xwt,   // [2][128][32][1600] f32
                                                  const float* __restrict__ whh_f, // [1600][400]
                                                  const float* __restrict__ whh_b,
                                                  const int* __restrict__ word_idxs,
                                                  float* __restrict__ hbuf,        // [2][2][400][32] f32
                                                  unsigned* __restrict__ flags,    // [2][128] u32
                                                  float* __restrict__ enc) {
  __shared__ __align__(16) double Wvd[4 * 400 * 4];   // [u][k][g] f64, 51,200 B
  __shared__ __align__(16) float  Shf[12800];          // h tile [k 0..399][b 0..31] f32, 51,200 B
  int bid = blockIdx.x;
  int d = bid / 100, slice = bid - d * 100;
  const float* whh = d ? whh_b : whh_f;
  const float* xwd = xwt + (size_t)d * SEQL * 32 * G4;
  unsigned* flg = flags + (size_t)d * 128;
  int t = threadIdx.x;

  // one-time: stage Whh rows for our 4 units x 4 gates into LDS as f64 [u][k][g]
  for (int pp = 0; pp < 16; ++pp) {
    int u = pp >> 2, g = pp & 3;
    const float* src = whh + (size_t)(g * 400 + slice * 4 + u) * 400;
    for (int k = t; k < 400; k += 256) Wvd[((size_t)u * 400 + k) * 4 + g] = (double)src[k];
  }

  int su = t >> 6;          // wave id = unit index within slice (0..3)
  int lane = t & 63;
  int kp = lane >> 4;       // k-phase (0..3) — high lane bits: conflict-free Shf reads
  int p  = lane & 15;       // batch-pair index (0..15)
  int sb2 = 2 * p;
  int kglob = slice * 4 + su;
  int cb = sb2 + kp;        // this thread's batch column (valid for kp<2)
  double cst = 0.0;

  if (kp < 2)
    astoref(&hbuf[((size_t)1 * 2 + d) * 12800 + (size_t)kglob * 32 + cb], 0.f);
  __syncthreads();                        // drain vmcnt (h init visible)
  if (t == 0) afstore(&flg[slice], 1u);   // publish #1 (initial h)

  for (int s = 0; s < SEQL; ++s) {
    int l = d ? (SEQL - 1 - s) : s;
    int rp = (s + 1) & 1, wp = s & 1;
    const float2* hr2 = (const float2*)(hbuf + ((size_t)rp * 2 + d) * 12800);
    float* hwb = hbuf + ((size_t)wp * 2 + d) * 12800;
    unsigned need = (unsigned)(s + 1);

    // prefetch xw gates + mask for (unit su, batch cb) — consumed at step end (latency hidden)
    float xw0 = 0.f, xw1 = 0.f, xw2 = 0.f, xw3 = 0.f;
    bool m = false;
    if (kp < 2) {
      const float* xp = xwd + ((size_t)l * 32 + cb) * G4 + kglob;
      xw0 = xp[0]; xw1 = xp[400]; xw2 = xp[800]; xw3 = xp[1200];
      m = word_idxs[cb * SEQL + l] > 0;
    }

    // wave 0 polls all 100 producer flags (50 lanes x 2); others wait at the barrier
    if (su == 0) {
      bool mine = lane < 50;
      const unsigned* fpa = flg + lane;
      const unsigned* fpb = flg + 50 + lane;
      while (true) {
        unsigned va = mine ? afload(fpa) : 0xFFFFFFFFu;
        unsigned vb = mine ? afload(fpb) : 0xFFFFFFFFu;
        if (__ballot((va < need) || (vb < need)) == 0ull) break;
        __builtin_amdgcn_s_sleep(1);
      }
    }
    __syncthreads();   // all 100 flags >= s+1; prior-step Shf consumption done

    // stage h tile (400x32 f32 = 6400 float2): issue ALL loads, write phase 1 (f2 idx<3072)
    float2 r[25];
#pragma unroll
    for (int j = 0; j < 25; ++j) r[j] = aload2f(&hr2[t + 256 * j]);
    float2* Shf2 = (float2*)Shf;
#pragma unroll
    for (int j = 0; j < 12; ++j) Shf2[t + 256 * j] = r[j];
    __syncthreads();   // phase-1 tile (k<192) ready

    double acc[8];
#pragma unroll
    for (int z = 0; z < 8; ++z) acc[z] = 0.0;
#pragma unroll 4
    for (int kk = 0; kk < 48; ++kk) {
      int klocal = 4 * kk + kp;
      float2 hp = *(const float2*)&Shf[(size_t)klocal * 32 + sb2];
      const double2* wrow = (const double2*)&Wvd[((size_t)su * 400 + klocal) * 4];
      double2 w01 = wrow[0];   // gates i,f
      double2 w23 = wrow[1];   // gates g,o
      double hx = (double)hp.x, hy = (double)hp.y;
      acc[0] = fma(w01.x, hx, acc[0]);
      acc[1] = fma(w01.x, hy, acc[1]);
      acc[2] = fma(w01.y, hx, acc[2]);
      acc[3] = fma(w01.y, hy, acc[3]);
      acc[4] = fma(w23.x, hx, acc[4]);
      acc[5] = fma(w23.x, hy, acc[5]);
      acc[6] = fma(w23.y, hx, acc[6]);
      acc[7] = fma(w23.y, hy, acc[7]);
    }

    // write phase-2 tile (disjoint LDS range; loads landed during phase-1 compute)
#pragma unroll
    for (int j = 12; j < 25; ++j) Shf2[t + 256 * j] = r[j];
    __syncthreads();   // phase-2 tile (k>=192) ready

#pragma unroll 4
    for (int kk = 48; kk < 100; ++kk) {
      int klocal = 4 * kk + kp;
      float2 hp = *(const float2*)&Shf[(size_t)klocal * 32 + sb2];
      const double2* wrow = (const double2*)&Wvd[((size_t)su * 400 + klocal) * 4];
      double2 w01 = wrow[0];
      double2 w23 = wrow[1];
      double hx = (double)hp.x, hy = (double)hp.y;
      acc[0] = fma(w01.x, hx, acc[0]);
      acc[1] = fma(w01.x, hy, acc[1]);
      acc[2] = fma(w01.y, hx, acc[2]);
      acc[3] = fma(w01.y, hy, acc[3]);
      acc[4] = fma(w23.x, hx, acc[4]);
      acc[5] = fma(w23.x, hy, acc[5]);
      acc[6] = fma(w23.y, hx, acc[6]);
      acc[7] = fma(w23.y, hy, acc[7]);
    }
    // reduce the 4-way k-split across kp groups (lane bits 4,5)
#pragma unroll
    for (int z = 0; z < 8; ++z) {
      acc[z] += __shfl_xor(acc[z], 16);
      acc[z] += __shfl_xor(acc[z], 32);
    }

    if (kp < 2) {
      double gi = acc[0 + kp] + (double)xw0;
      double gf = acc[2 + kp] + (double)xw1;
      double gg = acc[4 + kp] + (double)xw2;
      double go = acc[6 + kp] + (double)xw3;
      double si = (double)(1.f / (1.f + expf(-(float)gi)));
      double sf = (double)(1.f / (1.f + expf(-(float)gf)));
      double so = (double)(1.f / (1.f + expf(-(float)go)));
      double cn = sf * cst + si * (double)tanhf((float)gg);
      double hn = so * (double)tanhf((float)cn);
      float holdv = Shf[(size_t)kglob * 32 + cb];   // own published h from step s-1 (exact f32)
      float hv = m ? (float)hn : holdv;
      cst = m ? cn : cst;
      astoref(&hwb[(size_t)kglob * 32 + cb], hv);
      enc[((size_t)cb * SEQL + l) * 800 + d * 400 + kglob] = m ? (float)hn : 0.f;
    }
    __syncthreads();                          // drain vmcnt: h stores visible
    if (t == 0) afstore(&flg[slice], (unsigned)(s + 2));   // publish
  }
}

// ---------------- stage 2: score + argmax per (b,x), emits sort keys ----------------
__global__ __launch_bounds__(128) void k_stage2(const float* __restrict__ U,
                                                const float* __restrict__ y1T,
                                                const int* __restrict__ labels,
                                                unsigned long long* __restrict__ keys) {
  __shared__ double Ur[4644];
  int bx = blockIdx.x;
  int b = bx >> 7, x = bx & 127;
  const float* Urow = U + (size_t)bx * 4644;
  for (int i = threadIdx.x; i < 4644; i += 128) Ur[i] = (double)Urow[i];
  __syncthreads();
  int y = threadIdx.x;
  double acc[9];
#pragma unroll
  for (int o = 0; o < 9; ++o) acc[o] = 0.0;
  const float* yb = y1T + (size_t)b * 513 * 128 + y;
  for (int j = 0; j < 513; ++j) {
    double yv = (double)yb[(size_t)j * 128];
#pragma unroll
    for (int o = 0; o < 9; ++o) acc[o] = fma(Ur[o * 516 + j], yv, acc[o]);
  }
  double best = acc[0];
  int bi = 0;
#pragma unroll
  for (int o = 1; o < 9; ++o) {
    if (acc[o] > best) { best = acc[o]; bi = o; }
  }
  int fi = x * 128 + y;
  int lab = labels[(size_t)bx * 128 + y];
  bool valid = (bi != 1) && (lab > 0);
  unsigned long long key;
  if (valid) {
    unsigned long long u = (unsigned long long)__double_as_longlong(best);
    unsigned long long mm = (u >> 63) ? ~u : (u | 0x8000000000000000ull);
    unsigned long long dm = ~mm;
    key = (dm & ~0x3FFFFull) | ((unsigned long long)(unsigned)fi << 4) |
          (unsigned long long)(unsigned)bi;
  } else {
    key = ~0ull;
  }
  keys[(size_t)b * 16384 + fi] = key;
}

// ---------------- decode phase 1: sort 2048-key chunks (8 per sentence, 256 blocks total)
// Also initializes the output to NON_ENTITY=1 (coalesced, spread across all blocks).
__global__ __launch_bounds__(256) void k_sortchunks(unsigned long long* __restrict__ keysg,
                                                    int* __restrict__ outp) {
  __shared__ unsigned long long s[2048];
  int c = blockIdx.x, b = blockIdx.y;
  unsigned long long* kg = keysg + (size_t)b * 16384 + (size_t)c * 2048;
  int* ob = outp + (size_t)b * 16384 + (size_t)c * 2048;
  int t = threadIdx.x;
  for (int i = t; i < 2048; i += 256) s[i] = kg[i];
  for (int i = t; i < 2048; i += 256) ob[i] = 1;
  __syncthreads();
  for (int k = 2; k <= 2048; k <<= 1) {
    for (int j = k >> 1; j > 0; j >>= 1) {
#pragma unroll
      for (int p = 0; p < 4; ++p) {
        int ii = p * 256 + t;                       // compare index 0..1023
        int i = ((ii & ~(j - 1)) << 1) | (ii & (j - 1));
        int ix = i | j;
        bool up = ((i & k) == 0);
        unsigned long long a = s[i], bb = s[ix];
        if (up ? (a > bb) : (a < bb)) { s[i] = bb; s[ix] = a; }
      }
      __syncthreads();
    }
  }
  for (int i = t; i < 2048; i += 256) kg[i] = s[i];
}

// ---------------- decode phase 2: per-sentence merge 8x2048 -> 16384 (ascending) ----------------
__global__ __launch_bounds__(1024) void k_merge8(unsigned long long* __restrict__ keysg) {
  extern __shared__ unsigned long long m[];   // 8192 u64 = 64 KB
  int b = blockIdx.x;
  int t = threadIdx.x;
  unsigned long long* kg = keysg + (size_t)b * 16384;

  // Round A: merge pairs of 2048-runs -> 4096-runs (two pairs per pass, both ascending)
  for (int pass = 0; pass < 2; ++pass) {
    unsigned long long* base = kg + (size_t)pass * 8192;
    for (int i = t; i < 2048; i += 1024) {
      m[i]        = base[i];                    // run0 fwd
      m[2048 + i] = base[2048 + 2047 - i];      // run1 rev -> bitonic block 0
      m[4096 + i] = base[4096 + i];             // run2 fwd
      m[6144 + i] = base[6144 + 2047 - i];      // run3 rev -> bitonic block 1
    }
    __syncthreads();
    for (int j = 2048; j > 0; j >>= 1) {
#pragma unroll
      for (int p = 0; p < 4; ++p) {
        int ii = p * 1024 + t;                  // compare idx 0..4095 over 8192 elems
        int i = ((ii & ~(j - 1)) << 1) | (ii & (j - 1));
        int ix = i | j;
        unsigned long long a = m[i], c = m[ix];
        if (a > c) { m[i] = c; m[ix] = a; }     // ascending in both 4096-blocks
      }
      __syncthreads();
    }
    for (int i = t; i < 8192; i += 1024) base[i] = m[i];
    __syncthreads();
  }

  // Round B: merge 4096+4096 -> 8192; half 0 ascending, half 1 DESCENDING (sets up round C)
  for (int pass = 0; pass < 2; ++pass) {
    unsigned long long* base = kg + (size_t)pass * 8192;
    for (int i = t; i < 4096; i += 1024) {
      m[i]        = base[i];                    // fwd
      m[4096 + i] = base[4096 + 4095 - i];      // rev -> bitonic 8192
    }
    __syncthreads();
    bool desc = (pass == 1);
    for (int j = 4096; j > 0; j >>= 1) {
#pragma unroll
      for (int p = 0; p < 4; ++p) {
        int ii = p * 1024 + t;                  // compare idx 0..4095
        int i = ((ii & ~(j - 1)) << 1) | (ii & (j - 1));
        int ix = i | j;
        unsigned long long a = m[i], c = m[ix];
        if (desc ? (a < c) : (a > c)) { m[i] = c; m[ix] = a; }
      }
      __syncthreads();
    }
    for (int i = t; i < 8192; i += 1024) base[i] = m[i];
    __syncthreads();
  }

  // Round C: asc ++ desc = bitonic 16384. Global stage j=8192, then two 8192 LDS asc merges.
  for (int i = t; i < 8192; i += 1024) {
    unsigned long long a = kg[i], c = kg[i + 8192];
    if (a > c) { kg[i] = c; kg[i + 8192] = a; }
  }
  __syncthreads();
  for (int half = 0; half < 2; ++half) {
    unsigned long long* base = kg + (size_t)half * 8192;
    for (int i = t; i < 8192; i += 1024) m[i] = base[i];
    __syncthreads();
    for (int j = 4096; j > 0; j >>= 1) {
#pragma unroll
      for (int p = 0; p < 4; ++p) {
        int ii = p * 1024 + t;
        int i = ((ii & ~(j - 1)) << 1) | (ii & (j - 1));
        int ix = i | j;
        unsigned long long a = m[i], c = m[ix];
        if (a > c) { m[i] = c; m[ix] = a; }
      }
      __syncthreads();
    }
    for (int i = t; i < 8192; i += 1024) base[i] = m[i];
    __syncthreads();
  }
}

// ---------------- decode helpers ----------------
__device__ __forceinline__ void rangemask(int i, int j,
                                          unsigned long long& r0, unsigned long long& r1) {
  if (i > j) { r0 = 0ull; r1 = 0ull; return; }
  unsigned long long u0, u1;
  if (j >= 64) { u0 = ~0ull; u1 = (j >= 127) ? ~0ull : ((1ull << (j - 63)) - 1ull); }
  else         { u0 = (j == 63) ? ~0ull : ((1ull << (j + 1)) - 1ull); u1 = 0ull; }
  unsigned long long f0, f1;
  if (i >= 64) { f0 = 0ull; f1 = (~0ull) << (i - 64); }
  else         { f0 = (~0ull) << i; f1 = ~0ull; }
  r0 = u0 & f0; r1 = u1 & f1;
}

// ---------------- decode phase 3: batched greedy NMS scan (decision-equivalent to serial)
__global__ __launch_bounds__(64) void k_scan(const unsigned long long* __restrict__ keysg,
                                             int* __restrict__ outp) {
  int b = blockIdx.x;
  int lane = threadIdx.x;
  const unsigned long long* kg = keysg + (size_t)b * 16384;
  int* ob = outp + (size_t)b * 16384;
  unsigned long long s0 = 0, s1 = 0, in0 = 0, in1 = 0;

  for (int base = 0; base < 16384; base += 64) {
    unsigned long long key = kg[base + lane];
    bool valid = (key != ~0ull);
    if (__ballot(valid) == 0ull) break;          // keys ascending: rest invalid too
    int fi = (int)((key >> 4) & 0x3FFFull);
    int ci = fi >> 7, cj = fi & 127, ca = (int)(key & 15ull);
    bool isR = (ci <= cj);
    unsigned long long r0, r1; rangemask(ci, cj, r0, r1);
    unsigned long long rangeB = __ballot(isR);
    unsigned long long unp = __ballot(valid);

    while (unp) {
      bool insb = (((ci < 64) ? (in0 >> ci) : (in1 >> (ci - 64))) & 1ull) != 0;
      bool ovl = ((r0 & s0) | (r1 & s1)) != 0ull;
      bool myc = insb || (isR && ovl);
      unsigned long long confl = __ballot(myc);
      unp &= ~confl;                              // monotone -> permanent reject
      if (!unp) break;
      unsigned long long er = unp & rangeB;
      if (er == 0ull) {
        // all remaining are non-conflicting points: accept all, update starts, done
        if ((unp >> lane) & 1ull) ob[fi] = ca;
        unsigned long long c0 = 0, c1 = 0;
        if ((unp >> lane) & 1ull) { if (ci < 64) c0 = 1ull << ci; else c1 = 1ull << (ci - 64); }
#pragma unroll
        for (int off = 32; off; off >>= 1) { c0 |= __shfl_xor(c0, off); c1 |= __shfl_xor(c1, off); }
        s0 |= c0; s1 |= c1;
        break;
      }
      int r = __ffsll((long long)er) - 1;
      unsigned long long below = (r == 0) ? 0ull : ((1ull << r) - 1ull);
      unsigned long long pb = unp & below;        // all points (earlier ranges rejected/processed)
      if (pb) {
        if ((pb >> lane) & 1ull) ob[fi] = ca;
        unsigned long long c0 = 0, c1 = 0;
        if ((pb >> lane) & 1ull) { if (ci < 64) c0 = 1ull << ci; else c1 = 1ull << (ci - 64); }
#pragma unroll
        for (int off = 32; off; off >>= 1) { c0 |= __shfl_xor(c0, off); c1 |= __shfl_xor(c1, off); }
        s0 |= c0; s1 |= c1;
        unp &= ~pb;
      }
      // decide range candidate r against the updated starts
      int wi = __shfl(ci, r), wj = __shfl(cj, r), wa = __shfl(ca, r), wfi = __shfl(fi, r);
      unsigned long long rr0, rr1; rangemask(wi, wj, rr0, rr1);
      bool rin = (((wi < 64) ? (in0 >> wi) : (in1 >> (wi - 64))) & 1ull) != 0;
      bool rovl = ((rr0 & s0) | (rr1 & s1)) != 0ull;
      if (!(rin || rovl)) {
        if (lane == r) ob[wfi] = wa;
        if (wi < 64) s0 |= 1ull << wi; else s1 |= 1ull << (wi - 64);
        in0 |= rr0; in1 |= rr1;
      }
      unp &= ~(1ull << r);
    }
  }
}

extern "C" void kernel_launch(void* const* d_in, const int* in_sizes, int n_in,
                              void* d_out, int out_size, void* d_ws, size_t ws_size,
                              hipStream_t stream) {
  const int*   word_idxs = (const int*)d_in[0];
  const int*   labels    = (const int*)d_in[1];
  const float* word_emb  = (const float*)d_in[2];
  const float* Wih_f = (const float*)d_in[3];
  const float* Whh_f = (const float*)d_in[4];
  const float* bih_f = (const float*)d_in[5];
  const float* bhh_f = (const float*)d_in[6];
  const float* Wih_b = (const float*)d_in[7];
  const float* Whh_b = (const float*)d_in[8];
  const float* bih_b = (const float*)d_in[9];
  const float* bhh_b = (const float*)d_in[10];
  const float* W_start = (const float*)d_in[11];
  const float* b_start = (const float*)d_in[12];
  const float* W_end   = (const float*)d_in[13];
  const float* b_end   = (const float*)d_in[14];
  const float* W_bi    = (const float*)d_in[15];

  char* ws = (char*)d_ws;
  float* x    = (float*)(ws + OFF_X);
  float* hbuf = (float*)(ws + OFF_HBUF);
  unsigned* flags = (unsigned*)(ws + OFF_FLG);
  float* XWt  = (float*)(ws + OFF_XW);
  float* he   = (float*)(ws + OFF_HE);
  float* enc  = (float*)(ws + OFF_ENC);
  float* U    = (float*)(ws + OFF_U);
  float* x1   = (float*)(ws + OFF_X1);
  float* y1T  = (float*)(ws + OFF_Y1T);
  float* Wbp  = (float*)(ws + OFF_WBP);
  unsigned long long* keys = (unsigned long long*)(ws + OFF_KEYS);
  int* outp = (int*)d_out;

  // 1. embedding gather
  k_gather<<<4096, 256, 0, stream>>>(word_idxs, word_emb, x);
  // 2. input-gate GEMMs, bias folded, stored coalesced as XWt[d][l][b][1600]
  dim3 g2(32, 25);
  k_gemm_nt<<<g2, 256, 0, stream>>>(x, EMBD, Wih_f, EMBD, bih_f, bhh_f,
                                    XWt, 0, 4096, G4, EMBD, 2);
  k_gemm_nt<<<g2, 256, 0, stream>>>(x, EMBD, Wih_b, EMBD, bih_b, bhh_b,
                                    XWt + (size_t)SEQL * 32 * G4, 0, 4096, G4, EMBD, 2);
  // 3. flags zero (x region now dead), then persistent LSTM (flag-synced)
  hipMemsetAsync(ws + OFF_FLG, 0, 4096, stream);
  k_lstm3<<<NBLK, 256, 0, stream>>>(XWt, Whh_f, Whh_b, word_idxs, hbuf, flags, enc);
  // 4. projections: x1 (coalesced) and he (coalesced) -> y1T via LDS transpose
  dim3 g4(32, 8);
  k_gemm_nt<<<g4, 256, 0, stream>>>(enc, 800, W_start, 800, b_start, nullptr,
                                    x1, 516, 4096, FF, 800, 0);
  k_gemm_nt<<<g4, 256, 0, stream>>>(enc, 800, W_end, 800, b_end, nullptr,
                                    he, 512, 4096, FF, 800, 0);
  dim3 gt(16, 4, 32);
  k_y1t<<<gt, 256, 0, stream>>>(he, y1T);
  k_ones<<<32, 256, 0, stream>>>(x1, y1T);
  // 5. biaffine stage 1: U[b,x][o][j] = sum_i x1[b,x,i] W[o,i,j]
  k_wbpad<<<(9 * 513 * 516 + 255) / 256, 256, 0, stream>>>(W_bi, Wbp);
  dim3 g5(32, 9, 9);
  k_gemm_nn<<<g5, 256, 0, stream>>>(x1, 516, Wbp, 516, (size_t)513 * 516,
                                    U, 4644, 4096, 513, 513);
  // 6. stage 2 + argmax + key build
  k_stage2<<<4096, 128, 0, stream>>>(U, y1T, labels, keys);
  // 7. decode: chunk sort (full GPU) -> per-sentence merge -> batched NMS scan
  dim3 gs(8, 32);
  k_sortchunks<<<gs, 256, 0, stream>>>(keys, outp);
  k_merge8<<<32, 1024, 65536, stream>>>(keys);
  k_scan<<<32, 64, 0, stream>>>(keys, outp);
}

// Round 8
// 2066.498 us; speedup vs baseline: 1.4690x; 1.2727x over previous
//
#include <hip/hip_runtime.h>
#include <math.h>

// Problem constants
#define SEQL 128
#define NB   32
#define EMBD 300
#define HH   400      // hidden per direction
#define G4   1600     // 4*HH
#define FF   512
#define NLAB 9
#define NBLK 200      // persistent LSTM blocks: 2 dirs x 100 slices (4 hidden units each)

// ---------------- workspace layout (bytes) ----------------
static const size_t OFF_X    = 0;          // x [4096][300] f32 — dead after input GEMMs
static const size_t OFF_HBUF = 0;          // h double-buffer [2][2][400][32] f32 (204,800) — live only in k_lstm3
static const size_t OFF_FLG  = 1048576;    // publish flags [2][128] u32 — in dead x region
static const size_t OFF_XW   = 5242880;    // XWt [2][128][32][1600] f32 (52,428,800) dead after LSTM; he reuses it
static const size_t OFF_HE   = 5242880;    // he [4096][512] f32 (8,388,608) — after LSTM, before gemm_nn
static const size_t OFF_ENC  = 62914560;   // enc [4096][800] f32 (13,107,200) dead after proj GEMMs
static const size_t OFF_U    = 0;          // U [4096][9][516] f32 (76,087,296) overlays all of the above post-proj
static const size_t OFF_X1   = 76087296;   // x1 [4096][516] (8,454,144)
static const size_t OFF_Y1T  = 84541440;   // y1T [32][513][128] (8,404,992)
static const size_t OFF_KEYS = 92946432;   // keys u64 [32][16384] (4,194,304)
static const size_t OFF_WBP  = 97140736;   // Wb padded [9][513][516] (9,529,488)

// ---------------- agent-scope (IF-coherent, cache-bypassing) accessors ----------------
__device__ __forceinline__ float2 aload2f(const float2* p) {
  unsigned long long v = __hip_atomic_load((const unsigned long long*)p,
                                           __ATOMIC_RELAXED, __HIP_MEMORY_SCOPE_AGENT);
  union { unsigned long long u; float2 f; } c; c.u = v; return c.f;
}
__device__ __forceinline__ void astoref(float* p, float v) {
  __hip_atomic_store(p, v, __ATOMIC_RELAXED, __HIP_MEMORY_SCOPE_AGENT);
}
__device__ __forceinline__ unsigned afload(const unsigned* p) {
  return __hip_atomic_load(p, __ATOMIC_RELAXED, __HIP_MEMORY_SCOPE_AGENT);
}
__device__ __forceinline__ void afstore(unsigned* p, unsigned v) {
  __hip_atomic_store(p, v, __ATOMIC_RELAXED, __HIP_MEMORY_SCOPE_AGENT);
}

// ---------------- embedding gather ----------------
__global__ __launch_bounds__(256) void k_gather(const int* __restrict__ wi,
                                                const float* __restrict__ emb,
                                                float* __restrict__ x) {
  int m = blockIdx.x;
  int idx = wi[m];
  const float* src = emb + (size_t)idx * EMBD;
  float* dst = x + (size_t)m * EMBD;
  for (int e = threadIdx.x; e < EMBD; e += 256) dst[e] = src[e];
}

// ---------------- W_biaffine pad to stride 516 ----------------
__global__ __launch_bounds__(256) void k_wbpad(const float* __restrict__ wbi,
                                               float* __restrict__ wbp) {
  int tid = blockIdx.x * 256 + threadIdx.x;
  const int PER = 513 * 516;
  if (tid >= 9 * PER) return;
  int o = tid / PER;
  int r = tid - o * PER;
  int i = r / 516;
  int j = r - i * 516;
  wbp[tid] = (j < 513) ? wbi[(size_t)o * 513 * 513 + (size_t)i * 513 + j] : 0.f;
}

// ---------------- ones columns ----------------
__global__ __launch_bounds__(256) void k_ones(float* __restrict__ x1, float* __restrict__ y1T) {
  int tid = blockIdx.x * 256 + threadIdx.x;
  if (tid < 4096) {
    x1[(size_t)tid * 516 + 512] = 1.f;
  } else if (tid < 8192) {
    int r = tid - 4096;
    int bb = r >> 7, y = r & 127;
    y1T[((size_t)bb * 513 + 512) * 128 + y] = 1.f;
  }
}

// ---------------- he -> y1T transpose (coalesced both sides) ----------------
__global__ __launch_bounds__(256) void k_y1t(const float* __restrict__ he,
                                             float* __restrict__ y1T) {
  __shared__ float tile[32][33];
  int b = blockIdx.z;
  int n0 = blockIdx.x * 32, y0 = blockIdx.y * 32;
  int tx = threadIdx.x & 31, ty = threadIdx.x >> 5;
  for (int yy = ty; yy < 32; yy += 8)
    tile[yy][tx] = he[((size_t)b * 128 + y0 + yy) * 512 + n0 + tx];
  __syncthreads();
  for (int nn = ty; nn < 32; nn += 8)
    y1T[((size_t)b * 513 + n0 + nn) * 128 + y0 + tx] = tile[tx][nn];
}

// ---------------- tiled GEMM v9: f32 accumulate (matches reference precision; the f64
// variant was f64-pipe+cvt bound — 12 v_cvt + 32 f64-FMA/kk; f32 runs 2x FMA rate with
// zero cvt). 128x64 tile, 8x4 acc. mode 0: normal store; mode 2: XWt store [l][b][n].
__global__ __launch_bounds__(256) void k_gemm_nt(const float* __restrict__ A, int lda,
                                                 const float* __restrict__ W, int ldw,
                                                 const float* __restrict__ bias1,
                                                 const float* __restrict__ bias2,
                                                 float* __restrict__ C, int ldc,
                                                 int M, int N, int K, int mode) {
  __shared__ __align__(16) float As[16][132];
  __shared__ __align__(16) float Bs[16][68];
  int t = threadIdx.x;
  int m0 = blockIdx.x * 128, n0 = blockIdx.y * 64;
  int tm = t & 15, tn = t >> 4;
  int ar = t >> 1, akq = t & 1;      // A stage: row m0+ar, 8 floats at k0+8*akq
  int br = t >> 2, bkq = t & 3;      // B stage: row n0+br, 4 floats at k0+4*bkq
  float acc[8][4];
#pragma unroll
  for (int r = 0; r < 8; ++r)
#pragma unroll
    for (int c = 0; c < 4; ++c) acc[r][c] = 0.f;

  for (int k0 = 0; k0 < K; k0 += 16) {
    {
      const float* ap = A + (size_t)(m0 + ar) * lda + k0 + 8 * akq;
      float v[8];
      if (k0 + 8 * akq + 8 <= K) {
        float4 f0 = *(const float4*)ap;
        float4 f1 = *(const float4*)(ap + 4);
        v[0] = f0.x; v[1] = f0.y; v[2] = f0.z; v[3] = f0.w;
        v[4] = f1.x; v[5] = f1.y; v[6] = f1.z; v[7] = f1.w;
      } else {
#pragma unroll
        for (int i = 0; i < 8; ++i) v[i] = (k0 + 8 * akq + i < K) ? ap[i] : 0.f;
      }
#pragma unroll
      for (int i = 0; i < 8; ++i) As[8 * akq + i][ar] = v[i];
    }
    {
      int nr = n0 + br;
      float v0 = 0.f, v1 = 0.f, v2 = 0.f, v3 = 0.f;
      if (nr < N) {
        const float* wp = W + (size_t)nr * ldw + k0 + 4 * bkq;
        if (k0 + 4 * bkq + 4 <= K) {
          float4 f = *(const float4*)wp; v0 = f.x; v1 = f.y; v2 = f.z; v3 = f.w;
        } else {
          if (k0 + 4 * bkq + 0 < K) v0 = wp[0];
          if (k0 + 4 * bkq + 1 < K) v1 = wp[1];
          if (k0 + 4 * bkq + 2 < K) v2 = wp[2];
          if (k0 + 4 * bkq + 3 < K) v3 = wp[3];
        }
      }
      Bs[4 * bkq + 0][br] = v0; Bs[4 * bkq + 1][br] = v1;
      Bs[4 * bkq + 2][br] = v2; Bs[4 * bkq + 3][br] = v3;
    }
    __syncthreads();
#pragma unroll
    for (int kk = 0; kk < 16; ++kk) {
      float4 a0 = *(const float4*)&As[kk][4 * tm];
      float4 a1 = *(const float4*)&As[kk][64 + 4 * tm];
      float4 b4 = *(const float4*)&Bs[kk][4 * tn];
      float av[8] = {a0.x, a0.y, a0.z, a0.w, a1.x, a1.y, a1.z, a1.w};
      float bv[4] = {b4.x, b4.y, b4.z, b4.w};
#pragma unroll
      for (int r = 0; r < 8; ++r)
#pragma unroll
        for (int c = 0; c < 4; ++c) acc[r][c] = fmaf(av[r], bv[c], acc[r][c]);
    }
    __syncthreads();
  }
  float bn[4];
#pragma unroll
  for (int c = 0; c < 4; ++c) {
    int n = n0 + 4 * tn + c;
    float bv = 0.f;
    if (n < N) {
      if (bias1) bv += bias1[n];
      if (bias2) bv += bias2[n];
    }
    bn[c] = bv;
  }
  if (mode == 0) {
#pragma unroll
    for (int rr = 0; rr < 8; ++rr) {
      int m = m0 + ((rr < 4) ? (4 * tm + rr) : (64 + 4 * tm + rr - 4));
      float* cp = C + (size_t)m * ldc + n0 + 4 * tn;
      if (n0 + 4 * tn + 4 <= N) {
        float4 s = make_float4(acc[rr][0] + bn[0], acc[rr][1] + bn[1],
                               acc[rr][2] + bn[2], acc[rr][3] + bn[3]);
        *(float4*)cp = s;
      } else {
#pragma unroll
        for (int c = 0; c < 4; ++c)
          if (n0 + 4 * tn + c < N) cp[c] = acc[rr][c] + bn[c];
      }
    }
  } else {
    // XWt store: row = l*32 + b (m = b*128 + l), coalesced float4 in n
#pragma unroll
    for (int rr = 0; rr < 8; ++rr) {
      int m = m0 + ((rr < 4) ? (4 * tm + rr) : (64 + 4 * tm + rr - 4));
      int bb = m >> 7, l = m & 127;
      float* cp = C + ((size_t)l * 32 + bb) * G4 + n0 + 4 * tn;
      float4 s = make_float4(acc[rr][0] + bn[0], acc[rr][1] + bn[1],
                             acc[rr][2] + bn[2], acc[rr][3] + bn[3]);
      *(float4*)cp = s;
    }
  }
}

// ---------------- tiled GEMM v9: f32 accumulate, batched over o ----------------
__global__ __launch_bounds__(256) void k_gemm_nn(const float* __restrict__ A, int lda,
                                                 const float* __restrict__ Bm, int ldb,
                                                 size_t strideB,
                                                 float* __restrict__ C, int ldc,
                                                 int M, int N, int K) {
  __shared__ __align__(16) float As[16][132];
  __shared__ __align__(16) float Bs[16][68];
  int t = threadIdx.x;
  int o = blockIdx.z;
  const float* B = Bm + (size_t)o * strideB;
  float* Cb = C + (size_t)o * 516;
  int m0 = blockIdx.x * 128, n0 = blockIdx.y * 64;
  int tm = t & 15, tn = t >> 4;
  int ar = t >> 1, akq = t & 1;
  float acc[8][4];
#pragma unroll
  for (int r = 0; r < 8; ++r)
#pragma unroll
    for (int c = 0; c < 4; ++c) acc[r][c] = 0.f;

  for (int k0 = 0; k0 < K; k0 += 16) {
    {
      const float* ap = A + (size_t)(m0 + ar) * lda + k0 + 8 * akq;
      float v[8];
      if (k0 + 8 * akq + 8 <= K) {
        float4 f0 = *(const float4*)ap;
        float4 f1 = *(const float4*)(ap + 4);
        v[0] = f0.x; v[1] = f0.y; v[2] = f0.z; v[3] = f0.w;
        v[4] = f1.x; v[5] = f1.y; v[6] = f1.z; v[7] = f1.w;
      } else {
#pragma unroll
        for (int i = 0; i < 8; ++i) v[i] = (k0 + 8 * akq + i < K) ? ap[i] : 0.f;
      }
#pragma unroll
      for (int i = 0; i < 8; ++i) As[8 * akq + i][ar] = v[i];
    }
    {
      int kr = k0 + (t >> 4);
      int nc = n0 + 4 * (t & 15);
      float v0 = 0.f, v1 = 0.f, v2 = 0.f, v3 = 0.f;
      if (kr < K) {
        const float* bp = B + (size_t)kr * ldb + nc;
        if (nc + 4 <= N) {
          float4 f = *(const float4*)bp; v0 = f.x; v1 = f.y; v2 = f.z; v3 = f.w;
        } else {
          if (nc + 0 < N) v0 = bp[0];
          if (nc + 1 < N) v1 = bp[1];
          if (nc + 2 < N) v2 = bp[2];
          if (nc + 3 < N) v3 = bp[3];
        }
      }
      int kk = t >> 4, nq = 4 * (t & 15);
      Bs[kk][nq + 0] = v0; Bs[kk][nq + 1] = v1;
      Bs[kk][nq + 2] = v2; Bs[kk][nq + 3] = v3;
    }
    __syncthreads();
#pragma unroll
    for (int kk = 0; kk < 16; ++kk) {
      float4 a0 = *(const float4*)&As[kk][4 * tm];
      float4 a1 = *(const float4*)&As[kk][64 + 4 * tm];
      float4 b4 = *(const float4*)&Bs[kk][4 * tn];
      float av[8] = {a0.x, a0.y, a0.z, a0.w, a1.x, a1.y, a1.z, a1.w};
      float bv[4] = {b4.x, b4.y, b4.z, b4.w};
#pragma unroll
      for (int r = 0; r < 8; ++r)
#pragma unroll
        for (int c = 0; c < 4; ++c) acc[r][c] = fmaf(av[r], bv[c], acc[r][c]);
    }
    __syncthreads();
  }
#pragma unroll
  for (int rr = 0; rr < 8; ++rr) {
    int m = m0 + ((rr < 4) ? (4 * tm + rr) : (64 + 4 * tm + rr - 4));
    float* cp = Cb + (size_t)m * ldc + n0 + 4 * tn;
    if (n0 + 4 * tn + 4 <= N) {
      *(float4*)cp = make_float4(acc[rr][0], acc[rr][1], acc[rr][2], acc[rr][3]);
    } else {
#pragma unroll
      for (int c = 0; c < 4; ++c)
        if (n0 + 4 * tn + c < N) cp[c] = acc[rr][c];
    }
  }
}

// ---------------- persistent BiLSTM v6 (best known): f32 h-exchange + phase-split stage.
// v7 lesson: at 200-block scale, per-sync-round fixed cost (~2.5 µs) exceeds the latency
// it can hide — never increase sync-round count.
__global__ __launch_bounds__(256, 1) void k_lstm3(const float* __restrict__ xwt,   // [2][128][32][1600] f32
                                                  const float* __restrict__ whh_f, // [1600][400]
                                                  const float* __restrict__ whh_b,
                                                  const int* __restrict__ word_idxs,
                                                  float* __restrict__ hbuf,        // [2][2][400][32] f32
                                                  unsigned* __restrict__ flags,    // [2][128] u32
                                                  float* __restrict__ enc) {
  __shared__ __align__(16) double Wvd[4 * 400 * 4];   // [u][k][g] f64, 51,200 B
  __shared__ __align__(16) float  Shf[12800];          // h tile [k 0..399][b 0..31] f32, 51,200 B
  int bid = blockIdx.x;
  int d = bid / 100, slice = bid - d * 100;
  const float* whh = d ? whh_b : whh_f;
  const float* xwd = xwt + (size_t)d * SEQL * 32 * G4;
  unsigned* flg = flags + (size_t)d * 128;
  int t = threadIdx.x;

  // one-time: stage Whh rows for our 4 units x 4 gates into LDS as f64 [u][k][g]
  for (int pp = 0; pp < 16; ++pp) {
    int u = pp >> 2, g = pp & 3;
    const float* src = whh + (size_t)(g * 400 + slice * 4 + u) * 400;
    for (int k = t; k < 400; k += 256) Wvd[((size_t)u * 400 + k) * 4 + g] = (double)src[k];
  }

  int su = t >> 6;          // wave id = unit index within slice (0..3)
  int lane = t & 63;
  int kp = lane >> 4;       // k-phase (0..3) — high lane bits: conflict-free Shf reads
  int p  = lane & 15;       // batch-pair index (0..15)
  int sb2 = 2 * p;
  int kglob = slice * 4 + su;
  int cb = sb2 + kp;        // this thread's batch column (valid for kp<2)
  double cst = 0.0;

  if (kp < 2)
    astoref(&hbuf[((size_t)1 * 2 + d) * 12800 + (size_t)kglob * 32 + cb], 0.f);
  __syncthreads();                        // drain vmcnt (h init visible)
  if (t == 0) afstore(&flg[slice], 1u);   // publish #1 (initial h)

  for (int s = 0; s < SEQL; ++s) {
    int l = d ? (SEQL - 1 - s) : s;
    int rp = (s + 1) & 1, wp = s & 1;
    const float2* hr2 = (const float2*)(hbuf + ((size_t)rp * 2 + d) * 12800);
    float* hwb = hbuf + ((size_t)wp * 2 + d) * 12800;
    unsigned need = (unsigned)(s + 1);

    // prefetch xw gates + mask for (unit su, batch cb) — consumed at step end (latency hidden)
    float xw0 = 0.f, xw1 = 0.f, xw2 = 0.f, xw3 = 0.f;
    bool m = false;
    if (kp < 2) {
      const float* xp = xwd + ((size_t)l * 32 + cb) * G4 + kglob;
      xw0 = xp[0]; xw1 = xp[400]; xw2 = xp[800]; xw3 = xp[1200];
      m = word_idxs[cb * SEQL + l] > 0;
    }

    // wave 0 polls all 100 producer flags (50 lanes x 2); others wait at the barrier
    if (su == 0) {
      bool mine = lane < 50;
      const unsigned* fpa = flg + lane;
      const unsigned* fpb = flg + 50 + lane;
      while (true) {
        unsigned va = mine ? afload(fpa) : 0xFFFFFFFFu;
        unsigned vb = mine ? afload(fpb) : 0xFFFFFFFFu;
        if (__ballot((va < need) || (vb < need)) == 0ull) break;
        __builtin_amdgcn_s_sleep(1);
      }
    }
    __syncthreads();   // all 100 flags >= s+1; prior-step Shf consumption done

    // stage h tile (400x32 f32 = 6400 float2): issue ALL loads, write phase 1 (f2 idx<3072)
    float2 r[25];
#pragma unroll
    for (int j = 0; j < 25; ++j) r[j] = aload2f(&hr2[t + 256 * j]);
    float2* Shf2 = (float2*)Shf;
#pragma unroll
    for (int j = 0; j < 12; ++j) Shf2[t + 256 * j] = r[j];
    __syncthreads();   // phase-1 tile (k<192) ready

    double acc[8];
#pragma unroll
    for (int z = 0; z < 8; ++z) acc[z] = 0.0;
#pragma unroll 4
    for (int kk = 0; kk < 48; ++kk) {
      int klocal = 4 * kk + kp;
      float2 hp = *(const float2*)&Shf[(size_t)klocal * 32 + sb2];
      const double2* wrow = (const double2*)&Wvd[((size_t)su * 400 + klocal) * 4];
      double2 w01 = wrow[0];   // gates i,f
      double2 w23 = wrow[1];   // gates g,o
      double hx = (double)hp.x, hy = (double)hp.y;
      acc[0] = fma(w01.x, hx, acc[0]);
      acc[1] = fma(w01.x, hy, acc[1]);
      acc[2] = fma(w01.y, hx, acc[2]);
      acc[3] = fma(w01.y, hy, acc[3]);
      acc[4] = fma(w23.x, hx, acc[4]);
      acc[5] = fma(w23.x, hy, acc[5]);
      acc[6] = fma(w23.y, hx, acc[6]);
      acc[7] = fma(w23.y, hy, acc[7]);
    }

    // write phase-2 tile (disjoint LDS range; loads landed during phase-1 compute)
#pragma unroll
    for (int j = 12; j < 25; ++j) Shf2[t + 256 * j] = r[j];
    __syncthreads();   // phase-2 tile (k>=192) ready

#pragma unroll 4
    for (int kk = 48; kk < 100; ++kk) {
      int klocal = 4 * kk + kp;
      float2 hp = *(const float2*)&Shf[(size_t)klocal * 32 + sb2];
      const double2* wrow = (const double2*)&Wvd[((size_t)su * 400 + klocal) * 4];
      double2 w01 = wrow[0];
      double2 w23 = wrow[1];
      double hx = (double)hp.x, hy = (double)hp.y;
      acc[0] = fma(w01.x, hx, acc[0]);
      acc[1] = fma(w01.x, hy, acc[1]);
      acc[2] = fma(w01.y, hx, acc[2]);
      acc[3] = fma(w01.y, hy, acc[3]);
      acc[4] = fma(w23.x, hx, acc[4]);
      acc[5] = fma(w23.x, hy, acc[5]);
      acc[6] = fma(w23.y, hx, acc[6]);
      acc[7] = fma(w23.y, hy, acc[7]);
    }
    // reduce the 4-way k-split across kp groups (lane bits 4,5)
#pragma unroll
    for (int z = 0; z < 8; ++z) {
      acc[z] += __shfl_xor(acc[z], 16);
      acc[z] += __shfl_xor(acc[z], 32);
    }

    if (kp < 2) {
      double gi = acc[0 + kp] + (double)xw0;
      double gf = acc[2 + kp] + (double)xw1;
      double gg = acc[4 + kp] + (double)xw2;
      double go = acc[6 + kp] + (double)xw3;
      double si = (double)(1.f / (1.f + expf(-(float)gi)));
      double sf = (double)(1.f / (1.f + expf(-(float)gf)));
      double so = (double)(1.f / (1.f + expf(-(float)go)));
      double cn = sf * cst + si * (double)tanhf((float)gg);
      double hn = so * (double)tanhf((float)cn);
      float holdv = Shf[(size_t)kglob * 32 + cb];   // own published h from step s-1 (exact f32)
      float hv = m ? (float)hn : holdv;
      cst = m ? cn : cst;
      astoref(&hwb[(size_t)kglob * 32 + cb], hv);
      enc[((size_t)cb * SEQL + l) * 800 + d * 400 + kglob] = m ? (float)hn : 0.f;
    }
    __syncthreads();                          // drain vmcnt: h stores visible
    if (t == 0) afstore(&flg[slice], (unsigned)(s + 2));   // publish
  }
}

// ---------------- stage 2 v9: f32 compute (f32 LDS: 18.6 KB -> 2x occupancy; f32 FMA).
// Key built from (double)best — exact, monotone: sort semantics preserved for f32 order.
__global__ __launch_bounds__(128) void k_stage2(const float* __restrict__ U,
                                                const float* __restrict__ y1T,
                                                const int* __restrict__ labels,
                                                unsigned long long* __restrict__ keys) {
  __shared__ float Ur[4644];
  int bx = blockIdx.x;
  int b = bx >> 7, x = bx & 127;
  const float* Urow = U + (size_t)bx * 4644;
  for (int i = threadIdx.x; i < 4644; i += 128) Ur[i] = Urow[i];
  __syncthreads();
  int y = threadIdx.x;
  float acc[9];
#pragma unroll
  for (int o = 0; o < 9; ++o) acc[o] = 0.f;
  const float* yb = y1T + (size_t)b * 513 * 128 + y;
  for (int j = 0; j < 513; ++j) {
    float yv = yb[(size_t)j * 128];
#pragma unroll
    for (int o = 0; o < 9; ++o) acc[o] = fmaf(Ur[o * 516 + j], yv, acc[o]);
  }
  float best = acc[0];
  int bi = 0;
#pragma unroll
  for (int o = 1; o < 9; ++o) {
    if (acc[o] > best) { best = acc[o]; bi = o; }
  }
  int fi = x * 128 + y;
  int lab = labels[(size_t)bx * 128 + y];
  bool valid = (bi != 1) && (lab > 0);
  unsigned long long key;
  if (valid) {
    unsigned long long u = (unsigned long long)__double_as_longlong((double)best);
    unsigned long long mm = (u >> 63) ? ~u : (u | 0x8000000000000000ull);
    unsigned long long dm = ~mm;
    key = (dm & ~0x3FFFFull) | ((unsigned long long)(unsigned)fi << 4) |
          (unsigned long long)(unsigned)bi;
  } else {
    key = ~0ull;
  }
  keys[(size_t)b * 16384 + fi] = key;
}

// ---------------- decode phase 1: sort 2048-key chunks (8 per sentence, 256 blocks total)
// Also initializes the output to NON_ENTITY=1 (coalesced, spread across all blocks).
__global__ __launch_bounds__(256) void k_sortchunks(unsigned long long* __restrict__ keysg,
                                                    int* __restrict__ outp) {
  __shared__ unsigned long long s[2048];
  int c = blockIdx.x, b = blockIdx.y;
  unsigned long long* kg = keysg + (size_t)b * 16384 + (size_t)c * 2048;
  int* ob = outp + (size_t)b * 16384 + (size_t)c * 2048;
  int t = threadIdx.x;
  for (int i = t; i < 2048; i += 256) s[i] = kg[i];
  for (int i = t; i < 2048; i += 256) ob[i] = 1;
  __syncthreads();
  for (int k = 2; k <= 2048; k <<= 1) {
    for (int j = k >> 1; j > 0; j >>= 1) {
#pragma unroll
      for (int p = 0; p < 4; ++p) {
        int ii = p * 256 + t;                       // compare index 0..1023
        int i = ((ii & ~(j - 1)) << 1) | (ii & (j - 1));
        int ix = i | j;
        bool up = ((i & k) == 0);
        unsigned long long a = s[i], bb = s[ix];
        if (up ? (a > bb) : (a < bb)) { s[i] = bb; s[ix] = a; }
      }
      __syncthreads();
    }
  }
  for (int i = t; i < 2048; i += 256) kg[i] = s[i];
}

// ---------------- decode phase 2: per-sentence merge 8x2048 -> 16384 (ascending) ----------------
__global__ __launch_bounds__(1024) void k_merge8(unsigned long long* __restrict__ keysg) {
  extern __shared__ unsigned long long m[];   // 8192 u64 = 64 KB
  int b = blockIdx.x;
  int t = threadIdx.x;
  unsigned long long* kg = keysg + (size_t)b * 16384;

  // Round A: merge pairs of 2048-runs -> 4096-runs (two pairs per pass, both ascending)
  for (int pass = 0; pass < 2; ++pass) {
    unsigned long long* base = kg + (size_t)pass * 8192;
    for (int i = t; i < 2048; i += 1024) {
      m[i]        = base[i];                    // run0 fwd
      m[2048 + i] = base[2048 + 2047 - i];      // run1 rev -> bitonic block 0
      m[4096 + i] = base[4096 + i];             // run2 fwd
      m[6144 + i] = base[6144 + 2047 - i];      // run3 rev -> bitonic block 1
    }
    __syncthreads();
    for (int j = 2048; j > 0; j >>= 1) {
#pragma unroll
      for (int p = 0; p < 4; ++p) {
        int ii = p * 1024 + t;                  // compare idx 0..4095 over 8192 elems
        int i = ((ii & ~(j - 1)) << 1) | (ii & (j - 1));
        int ix = i | j;
        unsigned long long a = m[i], c = m[ix];
        if (a > c) { m[i] = c; m[ix] = a; }     // ascending in both 4096-blocks
      }
      __syncthreads();
    }
    for (int i = t; i < 8192; i += 1024) base[i] = m[i];
    __syncthreads();
  }

  // Round B: merge 4096+4096 -> 8192; half 0 ascending, half 1 DESCENDING (sets up round C)
  for (int pass = 0; pass < 2; ++pass) {
    unsigned long long* base = kg + (size_t)pass * 8192;
    for (int i = t; i < 4096; i += 1024) {
      m[i]        = base[i];                    // fwd
      m[4096 + i] = base[4096 + 4095 - i];      // rev -> bitonic 8192
    }
    __syncthreads();
    bool desc = (pass == 1);
    for (int j = 4096; j > 0; j >>= 1) {
#pragma unroll
      for (int p = 0; p < 4; ++p) {
        int ii = p * 1024 + t;                  // compare idx 0..4095
        int i = ((ii & ~(j - 1)) << 1) | (ii & (j - 1));
        int ix = i | j;
        unsigned long long a = m[i], c = m[ix];
        if (desc ? (a < c) : (a > c)) { m[i] = c; m[ix] = a; }
      }
      __syncthreads();
    }
    for (int i = t; i < 8192; i += 1024) base[i] = m[i];
    __syncthreads();
  }

  // Round C: asc ++ desc = bitonic 16384. Global stage j=8192, then two 8192 LDS asc merges.
  for (int i = t; i < 8192; i += 1024) {
    unsigned long long a = kg[i], c = kg[i + 8192];
    if (a > c) { kg[i] = c; kg[i + 8192] = a; }
  }
  __syncthreads();
  for (int half = 0; half < 2; ++half) {
    unsigned long long* base = kg + (size_t)half * 8192;
    for (int i = t; i < 8192; i += 1024) m[i] = base[i];
    __syncthreads();
    for (int j = 4096; j > 0; j >>= 1) {
#pragma unroll
      for (int p = 0; p < 4; ++p) {
        int ii = p * 1024 + t;
        int i = ((ii & ~(j - 1)) << 1) | (ii & (j - 1));
        int ix = i | j;
        unsigned long long a = m[i], c = m[ix];
        if (a > c) { m[i] = c; m[ix] = a; }
      }
      __syncthreads();
    }
    for (int i = t; i < 8192; i += 1024) base[i] = m[i];
    __syncthreads();
  }
}

// ---------------- decode helpers ----------------
__device__ __forceinline__ void rangemask(int i, int j,
                                          unsigned long long& r0, unsigned long long& r1) {
  if (i > j) { r0 = 0ull; r1 = 0ull; return; }
  unsigned long long u0, u1;
  if (j >= 64) { u0 = ~0ull; u1 = (j >= 127) ? ~0ull : ((1ull << (j - 63)) - 1ull); }
  else         { u0 = (j == 63) ? ~0ull : ((1ull << (j + 1)) - 1ull); u1 = 0ull; }
  unsigned long long f0, f1;
  if (i >= 64) { f0 = 0ull; f1 = (~0ull) << (i - 64); }
  else         { f0 = (~0ull) << i; f1 = ~0ull; }
  r0 = u0 & f0; r1 = u1 & f1;
}

// ---------------- decode phase 3: batched greedy NMS scan (decision-equivalent to serial)
__global__ __launch_bounds__(64) void k_scan(const unsigned long long* __restrict__ keysg,
                                             int* __restrict__ outp) {
  int b = blockIdx.x;
  int lane = threadIdx.x;
  const unsigned long long* kg = keysg + (size_t)b * 16384;
  int* ob = outp + (size_t)b * 16384;
  unsigned long long s0 = 0, s1 = 0, in0 = 0, in1 = 0;

  for (int base = 0; base < 16384; base += 64) {
    unsigned long long key = kg[base + lane];
    bool valid = (key != ~0ull);
    if (__ballot(valid) == 0ull) break;          // keys ascending: rest invalid too
    int fi = (int)((key >> 4) & 0x3FFFull);
    int ci = fi >> 7, cj = fi & 127, ca = (int)(key & 15ull);
    bool isR = (ci <= cj);
    unsigned long long r0, r1; rangemask(ci, cj, r0, r1);
    unsigned long long rangeB = __ballot(isR);
    unsigned long long unp = __ballot(valid);

    while (unp) {
      bool insb = (((ci < 64) ? (in0 >> ci) : (in1 >> (ci - 64))) & 1ull) != 0;
      bool ovl = ((r0 & s0) | (r1 & s1)) != 0ull;
      bool myc = insb || (isR && ovl);
      unsigned long long confl = __ballot(myc);
      unp &= ~confl;                              // monotone -> permanent reject
      if (!unp) break;
      unsigned long long er = unp & rangeB;
      if (er == 0ull) {
        // all remaining are non-conflicting points: accept all, update starts, done
        if ((unp >> lane) & 1ull) ob[fi] = ca;
        unsigned long long c0 = 0, c1 = 0;
        if ((unp >> lane) & 1ull) { if (ci < 64) c0 = 1ull << ci; else c1 = 1ull << (ci - 64); }
#pragma unroll
        for (int off = 32; off; off >>= 1) { c0 |= __shfl_xor(c0, off); c1 |= __shfl_xor(c1, off); }
        s0 |= c0; s1 |= c1;
        break;
      }
      int r = __ffsll((long long)er) - 1;
      unsigned long long below = (r == 0) ? 0ull : ((1ull << r) - 1ull);
      unsigned long long pb = unp & below;        // all points (earlier ranges rejected/processed)
      if (pb) {
        if ((pb >> lane) & 1ull) ob[fi] = ca;
        unsigned long long c0 = 0, c1 = 0;
        if ((pb >> lane) & 1ull) { if (ci < 64) c0 = 1ull << ci; else c1 = 1ull << (ci - 64); }
#pragma unroll
        for (int off = 32; off; off >>= 1) { c0 |= __shfl_xor(c0, off); c1 |= __shfl_xor(c1, off); }
        s0 |= c0; s1 |= c1;
        unp &= ~pb;
      }
      // decide range candidate r against the updated starts
      int wi = __shfl(ci, r), wj = __shfl(cj, r), wa = __shfl(ca, r), wfi = __shfl(fi, r);
      unsigned long long rr0, rr1; rangemask(wi, wj, rr0, rr1);
      bool rin = (((wi < 64) ? (in0 >> wi) : (in1 >> (wi - 64))) & 1ull) != 0;
      bool rovl = ((rr0 & s0) | (rr1 & s1)) != 0ull;
      if (!(rin || rovl)) {
        if (lane == r) ob[wfi] = wa;
        if (wi < 64) s0 |= 1ull << wi; else s1 |= 1ull << (wi - 64);
        in0 |= rr0; in1 |= rr1;
      }
      unp &= ~(1ull << r);
    }
  }
}

extern "C" void kernel_launch(void* const* d_in, const int* in_sizes, int n_in,
                              void* d_out, int out_size, void* d_ws, size_t ws_size,
                              hipStream_t stream) {
  const int*   word_idxs = (const int*)d_in[0];
  const int*   labels    = (const int*)d_in[1];
  const float* word_emb  = (const float*)d_in[2];
  const float* Wih_f = (const float*)d_in[3];
  const float* Whh_f = (const float*)d_in[4];
  const float* bih_f = (const float*)d_in[5];
  const float* bhh_f = (const float*)d_in[6];
  const float* Wih_b = (const float*)d_in[7];
  const float* Whh_b = (const float*)d_in[8];
  const float* bih_b = (const float*)d_in[9];
  const float* bhh_b = (const float*)d_in[10];
  const float* W_start = (const float*)d_in[11];
  const float* b_start = (const float*)d_in[12];
  const float* W_end   = (const float*)d_in[13];
  const float* b_end   = (const float*)d_in[14];
  const float* W_bi    = (const float*)d_in[15];

  char* ws = (char*)d_ws;
  float* x    = (float*)(ws + OFF_X);
  float* hbuf = (float*)(ws + OFF_HBUF);
  unsigned* flags = (unsigned*)(ws + OFF_FLG);
  float* XWt  = (float*)(ws + OFF_XW);
  float* he   = (float*)(ws + OFF_HE);
  float* enc  = (float*)(ws + OFF_ENC);
  float* U    = (float*)(ws + OFF_U);
  float* x1   = (float*)(ws + OFF_X1);
  float* y1T  = (float*)(ws + OFF_Y1T);
  float* Wbp  = (float*)(ws + OFF_WBP);
  unsigned long long* keys = (unsigned long long*)(ws + OFF_KEYS);
  int* outp = (int*)d_out;

  // 1. embedding gather
  k_gather<<<4096, 256, 0, stream>>>(word_idxs, word_emb, x);
  // 2. input-gate GEMMs, bias folded, stored coalesced as XWt[d][l][b][1600]
  dim3 g2(32, 25);
  k_gemm_nt<<<g2, 256, 0, stream>>>(x, EMBD, Wih_f, EMBD, bih_f, bhh_f,
                                    XWt, 0, 4096, G4, EMBD, 2);
  k_gemm_nt<<<g2, 256, 0, stream>>>(x, EMBD, Wih_b, EMBD, bih_b, bhh_b,
                                    XWt + (size_t)SEQL * 32 * G4, 0, 4096, G4, EMBD, 2);
  // 3. flags zero (x region now dead), then persistent LSTM (flag-synced)
  hipMemsetAsync(ws + OFF_FLG, 0, 4096, stream);
  k_lstm3<<<NBLK, 256, 0, stream>>>(XWt, Whh_f, Whh_b, word_idxs, hbuf, flags, enc);
  // 4. projections: x1 (coalesced) and he (coalesced) -> y1T via LDS transpose
  dim3 g4(32, 8);
  k_gemm_nt<<<g4, 256, 0, stream>>>(enc, 800, W_start, 800, b_start, nullptr,
                                    x1, 516, 4096, FF, 800, 0);
  k_gemm_nt<<<g4, 256, 0, stream>>>(enc, 800, W_end, 800, b_end, nullptr,
                                    he, 512, 4096, FF, 800, 0);
  dim3 gt(16, 4, 32);
  k_y1t<<<gt, 256, 0, stream>>>(he, y1T);
  k_ones<<<32, 256, 0, stream>>>(x1, y1T);
  // 5. biaffine stage 1: U[b,x][o][j] = sum_i x1[b,x,i] W[o,i,j]
  k_wbpad<<<(9 * 513 * 516 + 255) / 256, 256, 0, stream>>>(W_bi, Wbp);
  dim3 g5(32, 9, 9);
  k_gemm_nn<<<g5, 256, 0, stream>>>(x1, 516, Wbp, 516, (size_t)513 * 516,
                                    U, 4644, 4096, 513, 513);
  // 6. stage 2 + argmax + key build
  k_stage2<<<4096, 128, 0, stream>>>(U, y1T, labels, keys);
  // 7. decode: chunk sort (full GPU) -> per-sentence merge -> batched NMS scan
  dim3 gs(8, 32);
  k_sortchunks<<<gs, 256, 0, stream>>>(keys, outp);
  k_merge8<<<32, 1024, 65536, stream>>>(keys);
  k_scan<<<32, 64, 0, stream>>>(keys, outp);
}

// Round 9
// 1935.586 us; speedup vs baseline: 1.5684x; 1.0676x over previous
//
#include <hip/hip_runtime.h>
#include <math.h>

// Problem constants
#define SEQL 128
#define NB   32
#define EMBD 300
#define HH   400      // hidden per direction
#define G4   1600     // 4*HH
#define FF   512
#define NLAB 9
#define NBLK 200      // persistent LSTM blocks: 2 dirs x 100 slices (4 hidden units each)

// ---------------- workspace layout (bytes) ----------------
static const size_t OFF_X    = 0;          // x [4096][300] f32 — dead after input GEMMs
static const size_t OFF_HBUF = 0;          // h double-buffer [2][2][400][32] f32 (204,800) — live only in k_lstm3
static const size_t OFF_FLG  = 1048576;    // publish flags [2][128] u32 — in dead x region
static const size_t OFF_XW   = 5242880;    // XWt [2][128][32][1600] f32 (52,428,800) dead after LSTM; he reuses it
static const size_t OFF_HE   = 5242880;    // he [4096][512] f32 (8,388,608) — after LSTM, before gemm_nn
static const size_t OFF_ENC  = 62914560;   // enc [4096][800] f32 (13,107,200) dead after proj GEMMs
static const size_t OFF_U    = 0;          // U [4096][9][516] f32 (76,087,296) overlays all of the above post-proj
static const size_t OFF_X1   = 76087296;   // x1 [4096][516] (8,454,144)
static const size_t OFF_Y1T  = 84541440;   // y1T [32][513][128] (8,404,992)
static const size_t OFF_KEYS = 92946432;   // keys u64 [32][16384] (4,194,304)
static const size_t OFF_WBP  = 97140736;   // Wb padded [9][513][516] (9,529,488)

// ---------------- agent-scope (IF-coherent, cache-bypassing) accessors ----------------
__device__ __forceinline__ float2 aload2f(const float2* p) {
  unsigned long long v = __hip_atomic_load((const unsigned long long*)p,
                                           __ATOMIC_RELAXED, __HIP_MEMORY_SCOPE_AGENT);
  union { unsigned long long u; float2 f; } c; c.u = v; return c.f;
}
__device__ __forceinline__ void astoref(float* p, float v) {
  __hip_atomic_store(p, v, __ATOMIC_RELAXED, __HIP_MEMORY_SCOPE_AGENT);
}
__device__ __forceinline__ unsigned afload(const unsigned* p) {
  return __hip_atomic_load(p, __ATOMIC_RELAXED, __HIP_MEMORY_SCOPE_AGENT);
}
__device__ __forceinline__ void afstore(unsigned* p, unsigned v) {
  __hip_atomic_store(p, v, __ATOMIC_RELAXED, __HIP_MEMORY_SCOPE_AGENT);
}

// ---------------- embedding gather ----------------
__global__ __launch_bounds__(256) void k_gather(const int* __restrict__ wi,
                                                const float* __restrict__ emb,
                                                float* __restrict__ x) {
  int m = blockIdx.x;
  int idx = wi[m];
  const float* src = emb + (size_t)idx * EMBD;
  float* dst = x + (size_t)m * EMBD;
  for (int e = threadIdx.x; e < EMBD; e += 256) dst[e] = src[e];
}

// ---------------- W_biaffine pad to stride 516 ----------------
__global__ __launch_bounds__(256) void k_wbpad(const float* __restrict__ wbi,
                                               float* __restrict__ wbp) {
  int tid = blockIdx.x * 256 + threadIdx.x;
  const int PER = 513 * 516;
  if (tid >= 9 * PER) return;
  int o = tid / PER;
  int r = tid - o * PER;
  int i = r / 516;
  int j = r - i * 516;
  wbp[tid] = (j < 513) ? wbi[(size_t)o * 513 * 513 + (size_t)i * 513 + j] : 0.f;
}

// ---------------- ones columns ----------------
__global__ __launch_bounds__(256) void k_ones(float* __restrict__ x1, float* __restrict__ y1T) {
  int tid = blockIdx.x * 256 + threadIdx.x;
  if (tid < 4096) {
    x1[(size_t)tid * 516 + 512] = 1.f;
  } else if (tid < 8192) {
    int r = tid - 4096;
    int bb = r >> 7, y = r & 127;
    y1T[((size_t)bb * 513 + 512) * 128 + y] = 1.f;
  }
}

// ---------------- he -> y1T transpose (coalesced both sides) ----------------
__global__ __launch_bounds__(256) void k_y1t(const float* __restrict__ he,
                                             float* __restrict__ y1T) {
  __shared__ float tile[32][33];
  int b = blockIdx.z;
  int n0 = blockIdx.x * 32, y0 = blockIdx.y * 32;
  int tx = threadIdx.x & 31, ty = threadIdx.x >> 5;
  for (int yy = ty; yy < 32; yy += 8)
    tile[yy][tx] = he[((size_t)b * 128 + y0 + yy) * 512 + n0 + tx];
  __syncthreads();
  for (int nn = ty; nn < 32; nn += 8)
    y1T[((size_t)b * 513 + n0 + nn) * 128 + y0 + tx] = tile[tx][nn];
}

// ---------------- tiled GEMM v9: f32 accumulate. 128x64 tile, 8x4 acc.
// mode 0: normal store; mode 2: XWt store [l][b][n].
__global__ __launch_bounds__(256) void k_gemm_nt(const float* __restrict__ A, int lda,
                                                 const float* __restrict__ W, int ldw,
                                                 const float* __restrict__ bias1,
                                                 const float* __restrict__ bias2,
                                                 float* __restrict__ C, int ldc,
                                                 int M, int N, int K, int mode) {
  __shared__ __align__(16) float As[16][132];
  __shared__ __align__(16) float Bs[16][68];
  int t = threadIdx.x;
  int m0 = blockIdx.x * 128, n0 = blockIdx.y * 64;
  int tm = t & 15, tn = t >> 4;
  int ar = t >> 1, akq = t & 1;      // A stage: row m0+ar, 8 floats at k0+8*akq
  int br = t >> 2, bkq = t & 3;      // B stage: row n0+br, 4 floats at k0+4*bkq
  float acc[8][4];
#pragma unroll
  for (int r = 0; r < 8; ++r)
#pragma unroll
    for (int c = 0; c < 4; ++c) acc[r][c] = 0.f;

  for (int k0 = 0; k0 < K; k0 += 16) {
    {
      const float* ap = A + (size_t)(m0 + ar) * lda + k0 + 8 * akq;
      float v[8];
      if (k0 + 8 * akq + 8 <= K) {
        float4 f0 = *(const float4*)ap;
        float4 f1 = *(const float4*)(ap + 4);
        v[0] = f0.x; v[1] = f0.y; v[2] = f0.z; v[3] = f0.w;
        v[4] = f1.x; v[5] = f1.y; v[6] = f1.z; v[7] = f1.w;
      } else {
#pragma unroll
        for (int i = 0; i < 8; ++i) v[i] = (k0 + 8 * akq + i < K) ? ap[i] : 0.f;
      }
#pragma unroll
      for (int i = 0; i < 8; ++i) As[8 * akq + i][ar] = v[i];
    }
    {
      int nr = n0 + br;
      float v0 = 0.f, v1 = 0.f, v2 = 0.f, v3 = 0.f;
      if (nr < N) {
        const float* wp = W + (size_t)nr * ldw + k0 + 4 * bkq;
        if (k0 + 4 * bkq + 4 <= K) {
          float4 f = *(const float4*)wp; v0 = f.x; v1 = f.y; v2 = f.z; v3 = f.w;
        } else {
          if (k0 + 4 * bkq + 0 < K) v0 = wp[0];
          if (k0 + 4 * bkq + 1 < K) v1 = wp[1];
          if (k0 + 4 * bkq + 2 < K) v2 = wp[2];
          if (k0 + 4 * bkq + 3 < K) v3 = wp[3];
        }
      }
      Bs[4 * bkq + 0][br] = v0; Bs[4 * bkq + 1][br] = v1;
      Bs[4 * bkq + 2][br] = v2; Bs[4 * bkq + 3][br] = v3;
    }
    __syncthreads();
#pragma unroll
    for (int kk = 0; kk < 16; ++kk) {
      float4 a0 = *(const float4*)&As[kk][4 * tm];
      float4 a1 = *(const float4*)&As[kk][64 + 4 * tm];
      float4 b4 = *(const float4*)&Bs[kk][4 * tn];
      float av[8] = {a0.x, a0.y, a0.z, a0.w, a1.x, a1.y, a1.z, a1.w};
      float bv[4] = {b4.x, b4.y, b4.z, b4.w};
#pragma unroll
      for (int r = 0; r < 8; ++r)
#pragma unroll
        for (int c = 0; c < 4; ++c) acc[r][c] = fmaf(av[r], bv[c], acc[r][c]);
    }
    __syncthreads();
  }
  float bn[4];
#pragma unroll
  for (int c = 0; c < 4; ++c) {
    int n = n0 + 4 * tn + c;
    float bv = 0.f;
    if (n < N) {
      if (bias1) bv += bias1[n];
      if (bias2) bv += bias2[n];
    }
    bn[c] = bv;
  }
  if (mode == 0) {
#pragma unroll
    for (int rr = 0; rr < 8; ++rr) {
      int m = m0 + ((rr < 4) ? (4 * tm + rr) : (64 + 4 * tm + rr - 4));
      float* cp = C + (size_t)m * ldc + n0 + 4 * tn;
      if (n0 + 4 * tn + 4 <= N) {
        float4 s = make_float4(acc[rr][0] + bn[0], acc[rr][1] + bn[1],
                               acc[rr][2] + bn[2], acc[rr][3] + bn[3]);
        *(float4*)cp = s;
      } else {
#pragma unroll
        for (int c = 0; c < 4; ++c)
          if (n0 + 4 * tn + c < N) cp[c] = acc[rr][c] + bn[c];
      }
    }
  } else {
    // XWt store: row = l*32 + b (m = b*128 + l), coalesced float4 in n
#pragma unroll
    for (int rr = 0; rr < 8; ++rr) {
      int m = m0 + ((rr < 4) ? (4 * tm + rr) : (64 + 4 * tm + rr - 4));
      int bb = m >> 7, l = m & 127;
      float* cp = C + ((size_t)l * 32 + bb) * G4 + n0 + 4 * tn;
      float4 s = make_float4(acc[rr][0] + bn[0], acc[rr][1] + bn[1],
                             acc[rr][2] + bn[2], acc[rr][3] + bn[3]);
      *(float4*)cp = s;
    }
  }
}

// ---------------- tiled GEMM v9: f32 accumulate, batched over o ----------------
__global__ __launch_bounds__(256) void k_gemm_nn(const float* __restrict__ A, int lda,
                                                 const float* __restrict__ Bm, int ldb,
                                                 size_t strideB,
                                                 float* __restrict__ C, int ldc,
                                                 int M, int N, int K) {
  __shared__ __align__(16) float As[16][132];
  __shared__ __align__(16) float Bs[16][68];
  int t = threadIdx.x;
  int o = blockIdx.z;
  const float* B = Bm + (size_t)o * strideB;
  float* Cb = C + (size_t)o * 516;
  int m0 = blockIdx.x * 128, n0 = blockIdx.y * 64;
  int tm = t & 15, tn = t >> 4;
  int ar = t >> 1, akq = t & 1;
  float acc[8][4];
#pragma unroll
  for (int r = 0; r < 8; ++r)
#pragma unroll
    for (int c = 0; c < 4; ++c) acc[r][c] = 0.f;

  for (int k0 = 0; k0 < K; k0 += 16) {
    {
      const float* ap = A + (size_t)(m0 + ar) * lda + k0 + 8 * akq;
      float v[8];
      if (k0 + 8 * akq + 8 <= K) {
        float4 f0 = *(const float4*)ap;
        float4 f1 = *(const float4*)(ap + 4);
        v[0] = f0.x; v[1] = f0.y; v[2] = f0.z; v[3] = f0.w;
        v[4] = f1.x; v[5] = f1.y; v[6] = f1.z; v[7] = f1.w;
      } else {
#pragma unroll
        for (int i = 0; i < 8; ++i) v[i] = (k0 + 8 * akq + i < K) ? ap[i] : 0.f;
      }
#pragma unroll
      for (int i = 0; i < 8; ++i) As[8 * akq + i][ar] = v[i];
    }
    {
      int kr = k0 + (t >> 4);
      int nc = n0 + 4 * (t & 15);
      float v0 = 0.f, v1 = 0.f, v2 = 0.f, v3 = 0.f;
      if (kr < K) {
        const float* bp = B + (size_t)kr * ldb + nc;
        if (nc + 4 <= N) {
          float4 f = *(const float4*)bp; v0 = f.x; v1 = f.y; v2 = f.z; v3 = f.w;
        } else {
          if (nc + 0 < N) v0 = bp[0];
          if (nc + 1 < N) v1 = bp[1];
          if (nc + 2 < N) v2 = bp[2];
          if (nc + 3 < N) v3 = bp[3];
        }
      }
      int kk = t >> 4, nq = 4 * (t & 15);
      Bs[kk][nq + 0] = v0; Bs[kk][nq + 1] = v1;
      Bs[kk][nq + 2] = v2; Bs[kk][nq + 3] = v3;
    }
    __syncthreads();
#pragma unroll
    for (int kk = 0; kk < 16; ++kk) {
      float4 a0 = *(const float4*)&As[kk][4 * tm];
      float4 a1 = *(const float4*)&As[kk][64 + 4 * tm];
      float4 b4 = *(const float4*)&Bs[kk][4 * tn];
      float av[8] = {a0.x, a0.y, a0.z, a0.w, a1.x, a1.y, a1.z, a1.w};
      float bv[4] = {b4.x, b4.y, b4.z, b4.w};
#pragma unroll
      for (int r = 0; r < 8; ++r)
#pragma unroll
        for (int c = 0; c < 4; ++c) acc[r][c] = fmaf(av[r], bv[c], acc[r][c]);
    }
    __syncthreads();
  }
#pragma unroll
  for (int rr = 0; rr < 8; ++rr) {
    int m = m0 + ((rr < 4) ? (4 * tm + rr) : (64 + 4 * tm + rr - 4));
    float* cp = Cb + (size_t)m * ldc + n0 + 4 * tn;
    if (n0 + 4 * tn + 4 <= N) {
      *(float4*)cp = make_float4(acc[rr][0], acc[rr][1], acc[rr][2], acc[rr][3]);
    } else {
#pragma unroll
      for (int c = 0; c < 4; ++c)
        if (n0 + 4 * tn + c < N) cp[c] = acc[rr][c];
    }
  }
}

// ---------------- persistent BiLSTM v10: f32 GEMV (matches reference f32 precision).
// v9 post-mortem: the f64 Whh·h accumulation was ~2.2 µs of the 7.15 µs step — f64 FMA
// at half rate (4cy) + 200 v_cvt + 2x b128 Wvd reads. Reference computes this in f32;
// switching GEMV/gates to f32 removes all three (-~1.2 µs/step). c-state recurrence kept
// f64 (gate-phase only, trivial cost). Sync structure identical to v6 (v7 lesson: never
// increase sync-round count). Falsifier: absmax!=0 -> revert GEMV to f64.
__global__ __launch_bounds__(256, 1) void k_lstm3(const float* __restrict__ xwt,   // [2][128][32][1600] f32
                                                  const float* __restrict__ whh_f, // [1600][400]
                                                  const float* __restrict__ whh_b,
                                                  const int* __restrict__ word_idxs,
                                                  float* __restrict__ hbuf,        // [2][2][400][32] f32
                                                  unsigned* __restrict__ flags,    // [2][128] u32
                                                  float* __restrict__ enc) {
  __shared__ __align__(16) float Wvf[4 * 400 * 4];    // [u][k][g] f32, 25,600 B
  __shared__ __align__(16) float Shf[12800];           // h tile [k 0..399][b 0..31] f32, 51,200 B
  int bid = blockIdx.x;
  int d = bid / 100, slice = bid - d * 100;
  const float* whh = d ? whh_b : whh_f;
  const float* xwd = xwt + (size_t)d * SEQL * 32 * G4;
  unsigned* flg = flags + (size_t)d * 128;
  int t = threadIdx.x;

  // one-time: stage Whh rows for our 4 units x 4 gates into LDS as f32 [u][k][g]
  for (int pp = 0; pp < 16; ++pp) {
    int u = pp >> 2, g = pp & 3;
    const float* src = whh + (size_t)(g * 400 + slice * 4 + u) * 400;
    for (int k = t; k < 400; k += 256) Wvf[((size_t)u * 400 + k) * 4 + g] = src[k];
  }

  int su = t >> 6;          // wave id = unit index within slice (0..3)
  int lane = t & 63;
  int kp = lane >> 4;       // k-phase (0..3) — high lane bits: conflict-free Shf reads
  int p  = lane & 15;       // batch-pair index (0..15)
  int sb2 = 2 * p;
  int kglob = slice * 4 + su;
  int cb = sb2 + kp;        // this thread's batch column (valid for kp<2)
  double cst = 0.0;

  if (kp < 2)
    astoref(&hbuf[((size_t)1 * 2 + d) * 12800 + (size_t)kglob * 32 + cb], 0.f);
  __syncthreads();                        // drain vmcnt (h init visible)
  if (t == 0) afstore(&flg[slice], 1u);   // publish #1 (initial h)

  for (int s = 0; s < SEQL; ++s) {
    int l = d ? (SEQL - 1 - s) : s;
    int rp = (s + 1) & 1, wp = s & 1;
    const float2* hr2 = (const float2*)(hbuf + ((size_t)rp * 2 + d) * 12800);
    float* hwb = hbuf + ((size_t)wp * 2 + d) * 12800;
    unsigned need = (unsigned)(s + 1);

    // prefetch xw gates + mask for (unit su, batch cb) — consumed at step end (latency hidden)
    float xw0 = 0.f, xw1 = 0.f, xw2 = 0.f, xw3 = 0.f;
    bool m = false;
    if (kp < 2) {
      const float* xp = xwd + ((size_t)l * 32 + cb) * G4 + kglob;
      xw0 = xp[0]; xw1 = xp[400]; xw2 = xp[800]; xw3 = xp[1200];
      m = word_idxs[cb * SEQL + l] > 0;
    }

    // wave 0 polls all 100 producer flags (50 lanes x 2); others wait at the barrier
    if (su == 0) {
      bool mine = lane < 50;
      const unsigned* fpa = flg + lane;
      const unsigned* fpb = flg + 50 + lane;
      while (true) {
        unsigned va = mine ? afload(fpa) : 0xFFFFFFFFu;
        unsigned vb = mine ? afload(fpb) : 0xFFFFFFFFu;
        if (__ballot((va < need) || (vb < need)) == 0ull) break;
        __builtin_amdgcn_s_sleep(1);
      }
    }
    __syncthreads();   // all 100 flags >= s+1; prior-step Shf consumption done

    // stage h tile (400x32 f32 = 6400 float2): issue ALL loads, write phase 1 (f2 idx<3072)
    float2 r[25];
#pragma unroll
    for (int j = 0; j < 25; ++j) r[j] = aload2f(&hr2[t + 256 * j]);
    float2* Shf2 = (float2*)Shf;
#pragma unroll
    for (int j = 0; j < 12; ++j) Shf2[t + 256 * j] = r[j];
    __syncthreads();   // phase-1 tile (k<192) ready

    float acc[8];
#pragma unroll
    for (int z = 0; z < 8; ++z) acc[z] = 0.f;
#pragma unroll 4
    for (int kk = 0; kk < 48; ++kk) {
      int klocal = 4 * kk + kp;
      float2 hp = *(const float2*)&Shf[(size_t)klocal * 32 + sb2];
      float4 w4 = *(const float4*)&Wvf[((size_t)su * 400 + klocal) * 4];  // gates i,f,g,o
      acc[0] = fmaf(w4.x, hp.x, acc[0]);
      acc[1] = fmaf(w4.x, hp.y, acc[1]);
      acc[2] = fmaf(w4.y, hp.x, acc[2]);
      acc[3] = fmaf(w4.y, hp.y, acc[3]);
      acc[4] = fmaf(w4.z, hp.x, acc[4]);
      acc[5] = fmaf(w4.z, hp.y, acc[5]);
      acc[6] = fmaf(w4.w, hp.x, acc[6]);
      acc[7] = fmaf(w4.w, hp.y, acc[7]);
    }

    // write phase-2 tile (disjoint LDS range; loads landed during phase-1 compute)
#pragma unroll
    for (int j = 12; j < 25; ++j) Shf2[t + 256 * j] = r[j];
    __syncthreads();   // phase-2 tile (k>=192) ready

#pragma unroll 4
    for (int kk = 48; kk < 100; ++kk) {
      int klocal = 4 * kk + kp;
      float2 hp = *(const float2*)&Shf[(size_t)klocal * 32 + sb2];
      float4 w4 = *(const float4*)&Wvf[((size_t)su * 400 + klocal) * 4];
      acc[0] = fmaf(w4.x, hp.x, acc[0]);
      acc[1] = fmaf(w4.x, hp.y, acc[1]);
      acc[2] = fmaf(w4.y, hp.x, acc[2]);
      acc[3] = fmaf(w4.y, hp.y, acc[3]);
      acc[4] = fmaf(w4.z, hp.x, acc[4]);
      acc[5] = fmaf(w4.z, hp.y, acc[5]);
      acc[6] = fmaf(w4.w, hp.x, acc[6]);
      acc[7] = fmaf(w4.w, hp.y, acc[7]);
    }
    // reduce the 4-way k-split across kp groups (lane bits 4,5)
#pragma unroll
    for (int z = 0; z < 8; ++z) {
      acc[z] += __shfl_xor(acc[z], 16);
      acc[z] += __shfl_xor(acc[z], 32);
    }

    if (kp < 2) {
      float gi = acc[0 + kp] + xw0;
      float gf = acc[2 + kp] + xw1;
      float gg = acc[4 + kp] + xw2;
      float go = acc[6 + kp] + xw3;
      float si = 1.f / (1.f + expf(-gi));
      float sf = 1.f / (1.f + expf(-gf));
      float so = 1.f / (1.f + expf(-go));
      double cn = (double)sf * cst + (double)si * (double)tanhf(gg);
      float hnf = so * tanhf((float)cn);
      float holdv = Shf[(size_t)kglob * 32 + cb];   // own published h from step s-1 (exact f32)
      float hv = m ? hnf : holdv;
      cst = m ? cn : cst;
      astoref(&hwb[(size_t)kglob * 32 + cb], hv);
      enc[((size_t)cb * SEQL + l) * 800 + d * 400 + kglob] = m ? hnf : 0.f;
    }
    __syncthreads();                          // drain vmcnt: h stores visible
    if (t == 0) afstore(&flg[slice], (unsigned)(s + 2));   // publish
  }
}

// ---------------- stage 2 v9: f32 compute (f32 LDS: 18.6 KB -> 2x occupancy; f32 FMA).
// Key built from (double)best — exact, monotone: sort semantics preserved for f32 order.
__global__ __launch_bounds__(128) void k_stage2(const float* __restrict__ U,
                                                const float* __restrict__ y1T,
                                                const int* __restrict__ labels,
                                                unsigned long long* __restrict__ keys) {
  __shared__ float Ur[4644];
  int bx = blockIdx.x;
  int b = bx >> 7, x = bx & 127;
  const float* Urow = U + (size_t)bx * 4644;
  for (int i = threadIdx.x; i < 4644; i += 128) Ur[i] = Urow[i];
  __syncthreads();
  int y = threadIdx.x;
  float acc[9];
#pragma unroll
  for (int o = 0; o < 9; ++o) acc[o] = 0.f;
  const float* yb = y1T + (size_t)b * 513 * 128 + y;
  for (int j = 0; j < 513; ++j) {
    float yv = yb[(size_t)j * 128];
#pragma unroll
    for (int o = 0; o < 9; ++o) acc[o] = fmaf(Ur[o * 516 + j], yv, acc[o]);
  }
  float best = acc[0];
  int bi = 0;
#pragma unroll
  for (int o = 1; o < 9; ++o) {
    if (acc[o] > best) { best = acc[o]; bi = o; }
  }
  int fi = x * 128 + y;
  int lab = labels[(size_t)bx * 128 + y];
  bool valid = (bi != 1) && (lab > 0);
  unsigned long long key;
  if (valid) {
    unsigned long long u = (unsigned long long)__double_as_longlong((double)best);
    unsigned long long mm = (u >> 63) ? ~u : (u | 0x8000000000000000ull);
    unsigned long long dm = ~mm;
    key = (dm & ~0x3FFFFull) | ((unsigned long long)(unsigned)fi << 4) |
          (unsigned long long)(unsigned)bi;
  } else {
    key = ~0ull;
  }
  keys[(size_t)b * 16384 + fi] = key;
}

// ---------------- decode phase 1: sort 2048-key chunks (8 per sentence, 256 blocks total)
// Also initializes the output to NON_ENTITY=1 (coalesced, spread across all blocks).
__global__ __launch_bounds__(256) void k_sortchunks(unsigned long long* __restrict__ keysg,
                                                    int* __restrict__ outp) {
  __shared__ unsigned long long s[2048];
  int c = blockIdx.x, b = blockIdx.y;
  unsigned long long* kg = keysg + (size_t)b * 16384 + (size_t)c * 2048;
  int* ob = outp + (size_t)b * 16384 + (size_t)c * 2048;
  int t = threadIdx.x;
  for (int i = t; i < 2048; i += 256) s[i] = kg[i];
  for (int i = t; i < 2048; i += 256) ob[i] = 1;
  __syncthreads();
  for (int k = 2; k <= 2048; k <<= 1) {
    for (int j = k >> 1; j > 0; j >>= 1) {
#pragma unroll
      for (int p = 0; p < 4; ++p) {
        int ii = p * 256 + t;                       // compare index 0..1023
        int i = ((ii & ~(j - 1)) << 1) | (ii & (j - 1));
        int ix = i | j;
        bool up = ((i & k) == 0);
        unsigned long long a = s[i], bb = s[ix];
        if (up ? (a > bb) : (a < bb)) { s[i] = bb; s[ix] = a; }
      }
      __syncthreads();
    }
  }
  for (int i = t; i < 2048; i += 256) kg[i] = s[i];
}

// ---------------- decode phase 2: per-sentence merge 8x2048 -> 16384 (ascending) ----------------
__global__ __launch_bounds__(1024) void k_merge8(unsigned long long* __restrict__ keysg) {
  extern __shared__ unsigned long long m[];   // 8192 u64 = 64 KB
  int b = blockIdx.x;
  int t = threadIdx.x;
  unsigned long long* kg = keysg + (size_t)b * 16384;

  // Round A: merge pairs of 2048-runs -> 4096-runs (two pairs per pass, both ascending)
  for (int pass = 0; pass < 2; ++pass) {
    unsigned long long* base = kg + (size_t)pass * 8192;
    for (int i = t; i < 2048; i += 1024) {
      m[i]        = base[i];                    // run0 fwd
      m[2048 + i] = base[2048 + 2047 - i];      // run1 rev -> bitonic block 0
      m[4096 + i] = base[4096 + i];             // run2 fwd
      m[6144 + i] = base[6144 + 2047 - i];      // run3 rev -> bitonic block 1
    }
    __syncthreads();
    for (int j = 2048; j > 0; j >>= 1) {
#pragma unroll
      for (int p = 0; p < 4; ++p) {
        int ii = p * 1024 + t;                  // compare idx 0..4095 over 8192 elems
        int i = ((ii & ~(j - 1)) << 1) | (ii & (j - 1));
        int ix = i | j;
        unsigned long long a = m[i], c = m[ix];
        if (a > c) { m[i] = c; m[ix] = a; }     // ascending in both 4096-blocks
      }
      __syncthreads();
    }
    for (int i = t; i < 8192; i += 1024) base[i] = m[i];
    __syncthreads();
  }

  // Round B: merge 4096+4096 -> 8192; half 0 ascending, half 1 DESCENDING (sets up round C)
  for (int pass = 0; pass < 2; ++pass) {
    unsigned long long* base = kg + (size_t)pass * 8192;
    for (int i = t; i < 4096; i += 1024) {
      m[i]        = base[i];                    // fwd
      m[4096 + i] = base[4096 + 4095 - i];      // rev -> bitonic 8192
    }
    __syncthreads();
    bool desc = (pass == 1);
    for (int j = 4096; j > 0; j >>= 1) {
#pragma unroll
      for (int p = 0; p < 4; ++p) {
        int ii = p * 1024 + t;                  // compare idx 0..4095
        int i = ((ii & ~(j - 1)) << 1) | (ii & (j - 1));
        int ix = i | j;
        unsigned long long a = m[i], c = m[ix];
        if (desc ? (a < c) : (a > c)) { m[i] = c; m[ix] = a; }
      }
      __syncthreads();
    }
    for (int i = t; i < 8192; i += 1024) base[i] = m[i];
    __syncthreads();
  }

  // Round C: asc ++ desc = bitonic 16384. Global stage j=8192, then two 8192 LDS asc merges.
  for (int i = t; i < 8192; i += 1024) {
    unsigned long long a = kg[i], c = kg[i + 8192];
    if (a > c) { kg[i] = c; kg[i + 8192] = a; }
  }
  __syncthreads();
  for (int half = 0; half < 2; ++half) {
    unsigned long long* base = kg + (size_t)half * 8192;
    for (int i = t; i < 8192; i += 1024) m[i] = base[i];
    __syncthreads();
    for (int j = 4096; j > 0; j >>= 1) {
#pragma unroll
      for (int p = 0; p < 4; ++p) {
        int ii = p * 1024 + t;
        int i = ((ii & ~(j - 1)) << 1) | (ii & (j - 1));
        int ix = i | j;
        unsigned long long a = m[i], c = m[ix];
        if (a > c) { m[i] = c; m[ix] = a; }
      }
      __syncthreads();
    }
    for (int i = t; i < 8192; i += 1024) base[i] = m[i];
    __syncthreads();
  }
}

// ---------------- decode helpers ----------------
__device__ __forceinline__ void rangemask(int i, int j,
                                          unsigned long long& r0, unsigned long long& r1) {
  if (i > j) { r0 = 0ull; r1 = 0ull; return; }
  unsigned long long u0, u1;
  if (j >= 64) { u0 = ~0ull; u1 = (j >= 127) ? ~0ull : ((1ull << (j - 63)) - 1ull); }
  else         { u0 = (j == 63) ? ~0ull : ((1ull << (j + 1)) - 1ull); u1 = 0ull; }
  unsigned long long f0, f1;
  if (i >= 64) { f0 = 0ull; f1 = (~0ull) << (i - 64); }
  else         { f0 = (~0ull) << i; f1 = ~0ull; }
  r0 = u0 & f0; r1 = u1 & f1;
}

// ---------------- decode phase 3: batched greedy NMS scan (decision-equivalent to serial)
__global__ __launch_bounds__(64) void k_scan(const unsigned long long* __restrict__ keysg,
                                             int* __restrict__ outp) {
  int b = blockIdx.x;
  int lane = threadIdx.x;
  const unsigned long long* kg = keysg + (size_t)b * 16384;
  int* ob = outp + (size_t)b * 16384;
  unsigned long long s0 = 0, s1 = 0, in0 = 0, in1 = 0;

  for (int base = 0; base < 16384; base += 64) {
    unsigned long long key = kg[base + lane];
    bool valid = (key != ~0ull);
    if (__ballot(valid) == 0ull) break;          // keys ascending: rest invalid too
    int fi = (int)((key >> 4) & 0x3FFFull);
    int ci = fi >> 7, cj = fi & 127, ca = (int)(key & 15ull);
    bool isR = (ci <= cj);
    unsigned long long r0, r1; rangemask(ci, cj, r0, r1);
    unsigned long long rangeB = __ballot(isR);
    unsigned long long unp = __ballot(valid);

    while (unp) {
      bool insb = (((ci < 64) ? (in0 >> ci) : (in1 >> (ci - 64))) & 1ull) != 0;
      bool ovl = ((r0 & s0) | (r1 & s1)) != 0ull;
      bool myc = insb || (isR && ovl);
      unsigned long long confl = __ballot(myc);
      unp &= ~confl;                              // monotone -> permanent reject
      if (!unp) break;
      unsigned long long er = unp & rangeB;
      if (er == 0ull) {
        // all remaining are non-conflicting points: accept all, update starts, done
        if ((unp >> lane) & 1ull) ob[fi] = ca;
        unsigned long long c0 = 0, c1 = 0;
        if ((unp >> lane) & 1ull) { if (ci < 64) c0 = 1ull << ci; else c1 = 1ull << (ci - 64); }
#pragma unroll
        for (int off = 32; off; off >>= 1) { c0 |= __shfl_xor(c0, off); c1 |= __shfl_xor(c1, off); }
        s0 |= c0; s1 |= c1;
        break;
      }
      int r = __ffsll((long long)er) - 1;
      unsigned long long below = (r == 0) ? 0ull : ((1ull << r) - 1ull);
      unsigned long long pb = unp & below;        // all points (earlier ranges rejected/processed)
      if (pb) {
        if ((pb >> lane) & 1ull) ob[fi] = ca;
        unsigned long long c0 = 0, c1 = 0;
        if ((pb >> lane) & 1ull) { if (ci < 64) c0 = 1ull << ci; else c1 = 1ull << (ci - 64); }
#pragma unroll
        for (int off = 32; off; off >>= 1) { c0 |= __shfl_xor(c0, off); c1 |= __shfl_xor(c1, off); }
        s0 |= c0; s1 |= c1;
        unp &= ~pb;
      }
      // decide range candidate r against the updated starts
      int wi = __shfl(ci, r), wj = __shfl(cj, r), wa = __shfl(ca, r), wfi = __shfl(fi, r);
      unsigned long long rr0, rr1; rangemask(wi, wj, rr0, rr1);
      bool rin = (((wi < 64) ? (in0 >> wi) : (in1 >> (wi - 64))) & 1ull) != 0;
      bool rovl = ((rr0 & s0) | (rr1 & s1)) != 0ull;
      if (!(rin || rovl)) {
        if (lane == r) ob[wfi] = wa;
        if (wi < 64) s0 |= 1ull << wi; else s1 |= 1ull << (wi - 64);
        in0 |= rr0; in1 |= rr1;
      }
      unp &= ~(1ull << r);
    }
  }
}

extern "C" void kernel_launch(void* const* d_in, const int* in_sizes, int n_in,
                              void* d_out, int out_size, void* d_ws, size_t ws_size,
                              hipStream_t stream) {
  const int*   word_idxs = (const int*)d_in[0];
  const int*   labels    = (const int*)d_in[1];
  const float* word_emb  = (const float*)d_in[2];
  const float* Wih_f = (const float*)d_in[3];
  const float* Whh_f = (const float*)d_in[4];
  const float* bih_f = (const float*)d_in[5];
  const float* bhh_f = (const float*)d_in[6];
  const float* Wih_b = (const float*)d_in[7];
  const float* Whh_b = (const float*)d_in[8];
  const float* bih_b = (const float*)d_in[9];
  const float* bhh_b = (const float*)d_in[10];
  const float* W_start = (const float*)d_in[11];
  const float* b_start = (const float*)d_in[12];
  const float* W_end   = (const float*)d_in[13];
  const float* b_end   = (const float*)d_in[14];
  const float* W_bi    = (const float*)d_in[15];

  char* ws = (char*)d_ws;
  float* x    = (float*)(ws + OFF_X);
  float* hbuf = (float*)(ws + OFF_HBUF);
  unsigned* flags = (unsigned*)(ws + OFF_FLG);
  float* XWt  = (float*)(ws + OFF_XW);
  float* he   = (float*)(ws + OFF_HE);
  float* enc  = (float*)(ws + OFF_ENC);
  float* U    = (float*)(ws + OFF_U);
  float* x1   = (float*)(ws + OFF_X1);
  float* y1T  = (float*)(ws + OFF_Y1T);
  float* Wbp  = (float*)(ws + OFF_WBP);
  unsigned long long* keys = (unsigned long long*)(ws + OFF_KEYS);
  int* outp = (int*)d_out;

  // 1. embedding gather
  k_gather<<<4096, 256, 0, stream>>>(word_idxs, word_emb, x);
  // 2. input-gate GEMMs, bias folded, stored coalesced as XWt[d][l][b][1600]
  dim3 g2(32, 25);
  k_gemm_nt<<<g2, 256, 0, stream>>>(x, EMBD, Wih_f, EMBD, bih_f, bhh_f,
                                    XWt, 0, 4096, G4, EMBD, 2);
  k_gemm_nt<<<g2, 256, 0, stream>>>(x, EMBD, Wih_b, EMBD, bih_b, bhh_b,
                                    XWt + (size_t)SEQL * 32 * G4, 0, 4096, G4, EMBD, 2);
  // 3. flags zero (x region now dead), then persistent LSTM (flag-synced)
  hipMemsetAsync(ws + OFF_FLG, 0, 4096, stream);
  k_lstm3<<<NBLK, 256, 0, stream>>>(XWt, Whh_f, Whh_b, word_idxs, hbuf, flags, enc);
  // 4. projections: x1 (coalesced) and he (coalesced) -> y1T via LDS transpose
  dim3 g4(32, 8);
  k_gemm_nt<<<g4, 256, 0, stream>>>(enc, 800, W_start, 800, b_start, nullptr,
                                    x1, 516, 4096, FF, 800, 0);
  k_gemm_nt<<<g4, 256, 0, stream>>>(enc, 800, W_end, 800, b_end, nullptr,
                                    he, 512, 4096, FF, 800, 0);
  dim3 gt(16, 4, 32);
  k_y1t<<<gt, 256, 0, stream>>>(he, y1T);
  k_ones<<<32, 256, 0, stream>>>(x1, y1T);
  // 5. biaffine stage 1: U[b,x][o][j] = sum_i x1[b,x,i] W[o,i,j]
  k_wbpad<<<(9 * 513 * 516 + 255) / 256, 256, 0, stream>>>(W_bi, Wbp);
  dim3 g5(32, 9, 9);
  k_gemm_nn<<<g5, 256, 0, stream>>>(x1, 516, Wbp, 516, (size_t)513 * 516,
                                    U, 4644, 4096, 513, 513);
  // 6. stage 2 + argmax + key build
  k_stage2<<<4096, 128, 0, stream>>>(U, y1T, labels, keys);
  // 7. decode: chunk sort (full GPU) -> per-sentence merge -> batched NMS scan
  dim3 gs(8, 32);
  k_sortchunks<<<gs, 256, 0, stream>>>(keys, outp);
  k_merge8<<<32, 1024, 65536, stream>>>(keys);
  k_scan<<<32, 64, 0, stream>>>(keys, outp);
}